// Round 11
// baseline (221.608 us; speedup 1.0000x reference)
//
#include <hip/hip_runtime.h>
#include <math.h>

#define NROWS 16384  // B*T
#define DIM 128
#define NCODE 8192
#define EPSF 1e-12f

typedef float f32x4 __attribute__((ext_vector_type(4)));
typedef __bf16 bf16x8 __attribute__((ext_vector_type(8)));
typedef unsigned short u16x8 __attribute__((ext_vector_type(8)));

// ---------------- MFMA-path ws layout (float offsets) ----------------
// cb       : 0          (1048576)
// cnorm2   : 1048576    (8192)
// Wt       : 1056768    (16384)   [k][d] f32, scale folded in
// Zcat     : 1073152    (3145728 f32 slots = 16384*384 u16)  [rt128][kt12][128r][32k]
// CBcat    : 4218880    (1572864 f32 slots =  8192*384 u16)  [ct32][kt12][256c][32k]
// pval     : 5791744    (used 524288)  [32 tiles][16384 rows]
// pidx     : 6840320    (used 524288)
// partials : 7888896    (4096)
// end        7892992 floats = 31,571,968 bytes
#define WS_NEED_BYTES 31571968ull

// K = 384 = 12 k-tiles of 32.  Z segs: [hi|hi|lo]; CB segs: [hi|lo|hi].
// Within a chunk [R rows][32 k]: elem(r,k) at (r<<5) + (k ^ (((r>>1)&3)<<3)).
#define KT 12
#define TILEA 4096   // 128*32 elems per (row-tile, kt) chunk
#define TILEB 8192   // 256*32 elems per (code-tile, kt) chunk
#define KPB 2        // k-tiles per barrier-pair (BK=64) -> 48 KiB LDS
#define CHUNK (TILEA + TILEB)  // 12288 elems per staged k-tile

__device__ __forceinline__ float wave_sum(float x) {
#pragma unroll
  for (int off = 32; off > 0; off >>= 1) x += __shfl_xor(x, off, 64);
  return x;
}

__device__ __forceinline__ unsigned short f2bf(float x) {
  union { float f; unsigned int u; } v;
  v.f = x;
  unsigned int r = v.u + 0x7fffu + ((v.u >> 16) & 1u);
  return (unsigned short)(r >> 16);
}
__device__ __forceinline__ float bf2f(unsigned short h) {
  union { float f; unsigned int u; } v;
  v.u = ((unsigned int)h) << 16;
  return v.f;
}

__device__ __forceinline__ void gload_lds16(const unsigned short* g,
                                            unsigned short* l) {
  __builtin_amdgcn_global_load_lds(
      (const __attribute__((address_space(1))) void*)g,
      (__attribute__((address_space(3))) void*)l, 16, 0, 0);
}

// --- K0a (fused): zprep (blocks 0..3071) + wprep (blocks 3072..3103) -----
__global__ __launch_bounds__(256) void wz_kernel(
    const float* __restrict__ z, const float* __restrict__ v,
    const float* __restrict__ g, unsigned short* __restrict__ zcat,
    float* __restrict__ Wt) {
  const int b = blockIdx.x;
  if (b < 3072) {
    const int id = b * 256 + threadIdx.x;  // 16384*48 exact
    const int row = id / 48, s = id - row * 48;
    const int kt = s >> 2, s4 = s & 3;
    const int seg = kt >> 2;  // 0,1: hi   2: lo
    const int d0 = ((kt & 3) << 5) + (s4 << 3);
    const int r = row & 127, rt = row >> 7;
    const int slotsw = s4 ^ ((r >> 1) & 3);

    const float* zp = &z[(size_t)row * DIM + d0];
    u16x8 out;
#pragma unroll
    for (int i = 0; i < 8; ++i) {
      const float x = zp[i];
      unsigned short bb = f2bf(x);
      if (seg == 2) bb = f2bf(x - bf2f(bb));
      out[i] = bb;
    }
    *(u16x8*)&zcat[(size_t)(rt * KT + kt) * TILEA + (r << 5) +
                   (slotsw << 3)] = out;
  } else {
    const int tid = threadIdx.x;
    const int wid = tid >> 6, lane = tid & 63;
    const int d = (b - 3072) * 4 + wid;  // 128 d total
    const float v0 = v[d * DIM + lane], v1 = v[d * DIM + lane + 64];
    const float ss = wave_sum(fmaf(v0, v0, v1 * v1));
    const float sc = g[d] / sqrtf(ss);
    Wt[lane * DIM + d] = v0 * sc;
    Wt[(lane + 64) * DIM + d] = v1 * sc;
  }
}

// --- K0b: cb[c][d] = fc[c]·Wt[:,d] + b[d]; cnorm2; cbcat (256-code tiles)
__global__ __launch_bounds__(256, 2) void codebook_kernel(
    const float* __restrict__ fc, const float* __restrict__ Wt,
    const float* __restrict__ bias, float* __restrict__ cb,
    float* __restrict__ cnorm2, unsigned short* __restrict__ cbcat) {
  __shared__ float Ws[DIM][DIM];  // 64 KiB, [k][d]
  const int tid = threadIdx.x;
  for (int i = tid; i < 4096; i += 256)
    *(float4*)&Ws[0][i << 2] = *(const float4*)&Wt[i << 2];
  __syncthreads();

  const int lane = tid & 63, wid = tid >> 6;
  const int c0 = blockIdx.x * 16 + wid * 4;
  const float b0 = bias[lane], b1 = bias[lane + 64];

  for (int cc = 0; cc < 4; ++cc) {
    const int c = __builtin_amdgcn_readfirstlane(c0 + cc);
    float a0 = 0.f, a1 = 0.f;
    for (int k = 0; k < DIM; k += 4) {
      const float4 f4 = *(const float4*)&fc[c * DIM + k];
      a0 = fmaf(f4.x, Ws[k][lane], a0);
      a1 = fmaf(f4.x, Ws[k][lane + 64], a1);
      a0 = fmaf(f4.y, Ws[k + 1][lane], a0);
      a1 = fmaf(f4.y, Ws[k + 1][lane + 64], a1);
      a0 = fmaf(f4.z, Ws[k + 2][lane], a0);
      a1 = fmaf(f4.z, Ws[k + 2][lane + 64], a1);
      a0 = fmaf(f4.w, Ws[k + 3][lane], a0);
      a1 = fmaf(f4.w, Ws[k + 3][lane + 64], a1);
    }
    const float o0 = a0 + b0, o1 = a1 + b1;
    cb[c * DIM + lane] = o0;
    cb[c * DIM + lane + 64] = o1;
    const float ss = wave_sum(fmaf(o0, o0, o1 * o1));
    if (lane == 0) cnorm2[c] = ss;

    if (cbcat != nullptr) {
      const int ct = c >> 8, r = c & 255;
      const unsigned int swz = ((r >> 1) & 3) << 3;
      unsigned short* base = cbcat + (size_t)ct * (KT * TILEB);
#pragma unroll
      for (int h = 0; h < 2; ++h) {
        const int d = lane + 64 * h;
        const float val = h ? o1 : o0;
        const unsigned short hiv = f2bf(val);
        const unsigned short lov = f2bf(val - bf2f(hiv));
        const int ktl = d >> 5;
        const int off = (r << 5) + ((d & 31) ^ swz);
        base[ktl * TILEB + off] = hiv;        // seg0: hi (pairs Z hi)
        base[(4 + ktl) * TILEB + off] = lov;  // seg1: lo (pairs Z hi)
        base[(8 + ktl) * TILEB + off] = hiv;  // seg2: hi (pairs Z lo)
      }
    }
  }
}

// --- K1: MFMA distance GEMM + per-tile argmin ----------------------------
// 128x256 tile, BK=64 (KPB=2), 4 waves (2x2 grid; wave tile 64x128,
// acc[4][8]), single-buffer 48 KiB LDS, TARGET 3 blocks/CU:
// __launch_bounds__(256,3) gives the allocator a 170-reg budget; the
// compute loop is ni-outer/mi-inner so only ONE B-fragment is live
// (4 af + 1 bfr + 128 acc ~ 160 regs). 3 independent barrier groups/CU.
__global__ __launch_bounds__(256, 3) void mfma_argmin_kernel(
    const unsigned short* __restrict__ zcat,
    const unsigned short* __restrict__ cbcat,
    const float* __restrict__ cnorm2, float* __restrict__ pval,
    int* __restrict__ pidx) {
  __shared__ __align__(16) unsigned short S[KPB * CHUNK];  // 48 KiB

  const int xcd = blockIdx.x & 7, idx = blockIdx.x >> 3;  // 4096 % 8 == 0
  const int rt = xcd * 16 + (idx & 15);  // 0..127 row tile (128 rows)
  const int ct = idx >> 4;               // 0..31  code tile (256 codes)

  const int tid = threadIdx.x;
  const int lane = tid & 63, wid = tid >> 6;  // 4 waves
  const int wr = wid >> 1, wc = wid & 1;      // 2 x 2 wave grid
  const int l15 = lane & 15, lg = lane >> 4;
  const int tid8 = tid * 8;  // 256 thr x 8 elems = 2048/issue

  const unsigned short* Ag = zcat + (size_t)rt * (KT * TILEA);
  const unsigned short* Bg = cbcat + (size_t)ct * (KT * TILEB);

  f32x4 acc[4][8];
#pragma unroll
  for (int mi = 0; mi < 4; ++mi)
#pragma unroll
    for (int ni = 0; ni < 8; ++ni) acc[mi][ni] = f32x4{0.f, 0.f, 0.f, 0.f};

  int aoff[4], boff[8];
#pragma unroll
  for (int i = 0; i < 4; ++i) {
    const int ra = wr * 64 + i * 16 + l15;
    aoff[i] = (ra << 5) + ((lg ^ ((ra >> 1) & 3)) << 3);
  }
#pragma unroll
  for (int i = 0; i < 8; ++i) {
    const int rc = wc * 128 + i * 16 + l15;
    boff[i] = TILEA + (rc << 5) + ((lg ^ ((rc >> 1) & 3)) << 3);
  }

  for (int it = 0; it < KT / KPB; ++it) {
    __syncthreads();  // previous iteration's ds_reads complete
#pragma unroll
    for (int kk = 0; kk < KPB; ++kk) {
      const int kt = it * KPB + kk;
      const unsigned short* ag = Ag + kt * TILEA;
      const unsigned short* bg = Bg + kt * TILEB;
      unsigned short* la = &S[kk * CHUNK];
      unsigned short* lb = &S[kk * CHUNK + TILEA];
#pragma unroll
      for (int j = 0; j < 2; ++j)  // A chunk: 4096 elems = 2 issues
        gload_lds16(ag + j * 2048 + tid8, la + j * 2048 + tid8);
#pragma unroll
      for (int j = 0; j < 4; ++j)  // B chunk: 8192 elems = 4 issues
        gload_lds16(bg + j * 2048 + tid8, lb + j * 2048 + tid8);
    }
    __syncthreads();  // vmcnt(0) drain (once per BK=64)

#pragma unroll
    for (int kk = 0; kk < KPB; ++kk) {
      const int sb = kk * CHUNK;
      bf16x8 af[4];
#pragma unroll
      for (int i = 0; i < 4; ++i) af[i] = *(const bf16x8*)&S[sb + aoff[i]];
#pragma unroll
      for (int ni = 0; ni < 8; ++ni) {  // ni-outer: one bfr live at a time
        const bf16x8 bfr = *(const bf16x8*)&S[sb + boff[ni]];
#pragma unroll
        for (int mi = 0; mi < 4; ++mi)
          acc[mi][ni] = __builtin_amdgcn_mfma_f32_16x16x32_bf16(
              af[mi], bfr, acc[mi][ni], 0, 0, 0);
      }
    }
  }
  __syncthreads();  // full drain before LDS overlay

  // ---- epilogue: dist = cn - 2*dot ; argmin over this block's 256 codes
  float* exv = (float*)&S[0];  // [2][128] floats
  int* exi = (int*)&S[2048];   // [2][128] ints (byte offset 4096)

  float cn[8];
#pragma unroll
  for (int ni = 0; ni < 8; ++ni)
    cn[ni] = cnorm2[ct * 256 + wc * 128 + ni * 16 + l15];

#pragma unroll
  for (int mi = 0; mi < 4; ++mi) {
#pragma unroll
    for (int rg = 0; rg < 4; ++rg) {
      float bv = 3.4e38f;
      int bi = 0;
#pragma unroll
      for (int ni = 0; ni < 8; ++ni) {
        const float d = fmaf(-2.f, acc[mi][ni][rg], cn[ni]);
        if (d < bv) { bv = d; bi = ct * 256 + wc * 128 + ni * 16 + l15; }
      }
#pragma unroll
      for (int off = 1; off < 16; off <<= 1) {  // within l15 group
        const float ov = __shfl_xor(bv, off, 64);
        const int oi = __shfl_xor(bi, off, 64);
        if (ov < bv || (ov == bv && oi < bi)) { bv = ov; bi = oi; }
      }
      if (l15 == 0) {
        const int rloc = wr * 64 + mi * 16 + (lg << 2) + rg;
        exv[wc * 128 + rloc] = bv;
        exi[wc * 128 + rloc] = bi;
      }
    }
  }
  __syncthreads();
  if (tid < 128) {
    float bv = exv[tid];
    int bi = exi[tid];
    const float v1 = exv[128 + tid];
    if (v1 < bv) { bv = v1; bi = exi[128 + tid]; }  // tie -> wc=0 (lower code)
    const int row = rt * 128 + tid;
    pval[(size_t)ct * NROWS + row] = bv;
    pidx[(size_t)ct * NROWS + row] = bi;
  }
}

// ===================== fallback path kernels (round-1 style) =============
__global__ void wprep_kernel(const float* __restrict__ v,
                             const float* __restrict__ g,
                             float* __restrict__ Wt) {
  const int d = blockIdx.x;
  const int lane = threadIdx.x;
  const float v0 = v[d * DIM + lane], v1 = v[d * DIM + lane + 64];
  const float ss = wave_sum(fmaf(v0, v0, v1 * v1));
  const float sc = g[d] / sqrtf(ss);
  Wt[lane * DIM + d] = v0 * sc;
  Wt[(lane + 64) * DIM + d] = v1 * sc;
}

__global__ __launch_bounds__(256, 1) void argmin_kernel(
    const float* __restrict__ z, const float* __restrict__ cb,
    const float* __restrict__ cnorm2, float* __restrict__ pval,
    int* __restrict__ pidx) {
  __shared__ float zs[128][DIM];
  __shared__ float cs[128][DIM];

  const int tid = threadIdx.x;
  const int rb = blockIdx.x >> 1;
  const int ch = blockIdx.x & 1;
  const int row0 = rb * 128;
  const int code0 = ch * (NCODE / 2);

  for (int i = tid; i < 128 * 32; i += 256) {
    const int r = i >> 5, f = i & 31;
    *(float4*)&zs[r][f << 2] = *(const float4*)&z[(row0 + r) * DIM + (f << 2)];
  }

  const int tx = tid & 15, ty = tid >> 4;
  const int sw = tx & 7;

  float best[8];
  int besti[8];
#pragma unroll
  for (int r = 0; r < 8; ++r) { best[r] = 3.4e38f; besti[r] = 0; }

  for (int cc = 0; cc < NCODE / 2; cc += 128) {
    __syncthreads();
    for (int i = tid; i < 128 * 32; i += 256) {
      const int r = i >> 5, f = i & 31;
      const int fg = f ^ (r & 7);
      *(float4*)&cs[r][f << 2] =
          *(const float4*)&cb[(code0 + cc + r) * DIM + (fg << 2)];
    }
    __syncthreads();

    float acc[8][8];
#pragma unroll
    for (int r = 0; r < 8; ++r)
#pragma unroll
      for (int j = 0; j < 8; ++j) acc[r][j] = 0.f;

    for (int k = 0; k < DIM; k += 4) {
      const int f = k >> 2;
      float4 zr[8], cr[8];
#pragma unroll
      for (int r = 0; r < 8; ++r) zr[r] = *(const float4*)&zs[ty + 16 * r][k];
      const int col = ((f ^ sw) << 2);
#pragma unroll
      for (int j = 0; j < 8; ++j) cr[j] = *(const float4*)&cs[tx + 16 * j][col];
#pragma unroll
      for (int r = 0; r < 8; ++r)
#pragma unroll
        for (int j = 0; j < 8; ++j) {
          acc[r][j] = fmaf(zr[r].x, cr[j].x, acc[r][j]);
          acc[r][j] = fmaf(zr[r].y, cr[j].y, acc[r][j]);
          acc[r][j] = fmaf(zr[r].z, cr[j].z, acc[r][j]);
          acc[r][j] = fmaf(zr[r].w, cr[j].w, acc[r][j]);
        }
    }

#pragma unroll
    for (int j = 0; j < 8; ++j) {
      const int code = code0 + cc + tx + 16 * j;
      const float cnv = cnorm2[code];
#pragma unroll
      for (int r = 0; r < 8; ++r) {
        const float s = fmaf(-2.f, acc[r][j], cnv);
        if (s < best[r]) { best[r] = s; besti[r] = code; }
      }
    }
  }

#pragma unroll
  for (int off = 1; off < 16; off <<= 1) {
#pragma unroll
    for (int r = 0; r < 8; ++r) {
      const float ov = __shfl_xor(best[r], off, 64);
      const int oi = __shfl_xor(besti[r], off, 64);
      if (ov < best[r] || (ov == best[r] && oi < besti[r])) {
        best[r] = ov;
        besti[r] = oi;
      }
    }
  }
  if (tx == 0) {
#pragma unroll
    for (int r = 0; r < 8; ++r) {
      const int row = row0 + ty + 16 * r;
      pval[(size_t)ch * NROWS + row] = best[r];
      pidx[(size_t)ch * NROWS + row] = besti[r];
    }
  }
}

// --- shared rotation body -------------------------------------------------
__device__ __forceinline__ float rotate_row(const float* __restrict__ z,
                                            const float* __restrict__ cb,
                                            int row, int ci, int lane,
                                            float* __restrict__ out_zq,
                                            float* __restrict__ out_idx) {
  const float z0 = z[row * DIM + lane], z1 = z[row * DIM + lane + 64];
  const float c0 = cb[ci * DIM + lane], c1 = cb[ci * DIM + lane + 64];

  const float ns2 = wave_sum(fmaf(z0, z0, z1 * z1));
  const float nt2 = wave_sum(fmaf(c0, c0, c1 * c1));
  const float ns = sqrtf(ns2), nt = sqrtf(nt2);
  const float dns = fmaxf(ns, EPSF), dnt = fmaxf(nt, EPSF);
  const float u0 = z0 / dns, u1 = z1 / dns;
  const float q0 = c0 / dnt, q1 = c1 / dnt;
  float w0 = u0 + q0, w1 = u1 + q1;
  const float nw = sqrtf(wave_sum(fmaf(w0, w0, w1 * w1)));
  const float dnw = fmaxf(nw, EPSF);
  w0 /= dnw;
  w1 /= dnw;
  const float ew = wave_sum(fmaf(z0, w0, z1 * w1));
  const float eu = wave_sum(fmaf(z0, u0, z1 * u1));
  const float sc = nt / dns;
  const float o0 = (z0 - 2.f * ew * w0 + 2.f * eu * q0) * sc;
  const float o1 = (z1 - 2.f * ew * w1 + 2.f * eu * q1) * sc;
  out_zq[row * DIM + lane] = o0;
  out_zq[row * DIM + lane + 64] = o1;
  if (lane == 0) out_idx[row] = (float)ci;

  const float d0 = z0 - c0, d1 = z1 - c1;
  return wave_sum(fmaf(d0, d0, d1 * d1));
}

// --- K2 (main): 16 rows per block, wave loops 4 rows ----------------------
__global__ __launch_bounds__(256) void rotate16_kernel(
    const float* __restrict__ z, const float* __restrict__ cb,
    const float* __restrict__ pval, const int* __restrict__ pidx,
    float* __restrict__ out_zq, float* __restrict__ out_idx,
    float* __restrict__ partials) {
  const int tid = threadIdx.x;
  const int wid = tid >> 6, lane = tid & 63;
  float acc = 0.f;
#pragma unroll
  for (int j = 0; j < 4; ++j) {
    const int row = blockIdx.x * 16 + wid * 4 + j;
    // lane-parallel reduce over 32 code-tile partials
    float bv = 3.4e38f;
    int bi = 0x7fffffff;
    if (lane < 32) {
      bv = pval[(size_t)lane * NROWS + row];
      bi = pidx[(size_t)lane * NROWS + row];
    }
#pragma unroll
    for (int off = 32; off > 0; off >>= 1) {
      const float ov = __shfl_xor(bv, off, 64);
      const int oi = __shfl_xor(bi, off, 64);
      if (ov < bv || (ov == bv && oi < bi)) { bv = ov; bi = oi; }
    }
    acc += rotate_row(z, cb, row, bi, lane, out_zq, out_idx);
  }
  __shared__ float pr[4];
  if (lane == 0) pr[wid] = acc;
  __syncthreads();
  if (tid == 0) partials[blockIdx.x] = (pr[0] + pr[1]) + (pr[2] + pr[3]);
}

// --- K2 (fallback): 4 rows per block --------------------------------------
__global__ __launch_bounds__(256) void rotate_kernel(
    const float* __restrict__ z, const float* __restrict__ cb,
    const float* __restrict__ pval, const int* __restrict__ pidx, int ntiles,
    float* __restrict__ out_zq, float* __restrict__ out_idx,
    float* __restrict__ partials) {
  const int tid = threadIdx.x;
  const int wid = tid >> 6, lane = tid & 63;
  const int row = blockIdx.x * 4 + wid;

  float bv = 3.4e38f;
  int bi = 0x7fffffff;
  if (lane < ntiles) {
    bv = pval[(size_t)lane * NROWS + row];
    bi = pidx[(size_t)lane * NROWS + row];
  }
#pragma unroll
  for (int off = 32; off > 0; off >>= 1) {
    const float ov = __shfl_xor(bv, off, 64);
    const int oi = __shfl_xor(bi, off, 64);
    if (ov < bv || (ov == bv && oi < bi)) { bv = ov; bi = oi; }
  }
  const float rsum = rotate_row(z, cb, row, bi, lane, out_zq, out_idx);
  __shared__ float pr[4];
  if (lane == 0) pr[wid] = rsum;
  __syncthreads();
  if (tid == 0) partials[blockIdx.x] = (pr[0] + pr[1]) + (pr[2] + pr[3]);
}

// --- K3: deterministic final reduction for commit ------------------------
__global__ void finalize_kernel(const float* __restrict__ partials, int n,
                                float* __restrict__ out_commit) {
  __shared__ float red[256];
  const int tid = threadIdx.x;
  float s = 0.f;
  for (int i = tid; i < n; i += 256) s += partials[i];
  red[tid] = s;
  __syncthreads();
  for (int off = 128; off > 0; off >>= 1) {
    if (tid < off) red[tid] += red[tid + off];
    __syncthreads();
  }
  if (tid == 0) out_commit[0] = red[0] * (1.25f / ((float)NROWS * (float)DIM));
}

extern "C" void kernel_launch(void* const* d_in, const int* in_sizes, int n_in,
                              void* d_out, int out_size, void* d_ws,
                              size_t ws_size, hipStream_t stream) {
  const float* z = (const float*)d_in[0];
  const float* fc = (const float*)d_in[1];
  const float* conv_v = (const float*)d_in[2];
  const float* conv_g = (const float*)d_in[3];
  const float* conv_b = (const float*)d_in[4];
  float* out = (float*)d_out;  // [zq 2097152][idx 16384][commit 1]

  float* ws = (float*)d_ws;
  float* cb = ws;
  float* cnorm2 = ws + 1048576;
  float* Wt = ws + 1056768;

  if (ws_size >= WS_NEED_BYTES) {
    unsigned short* zcat = (unsigned short*)(ws + 1073152);
    unsigned short* cbcat = (unsigned short*)(ws + 4218880);
    float* pval = ws + 5791744;
    int* pidx = (int*)(ws + 6840320);
    float* partials = ws + 7888896;

    wz_kernel<<<3104, 256, 0, stream>>>(z, conv_v, conv_g, zcat, Wt);
    codebook_kernel<<<NCODE / 16, 256, 0, stream>>>(fc, Wt, conv_b, cb, cnorm2,
                                                    cbcat);
    mfma_argmin_kernel<<<4096, 256, 0, stream>>>(zcat, cbcat, cnorm2, pval,
                                                 pidx);
    rotate16_kernel<<<NROWS / 16, 256, 0, stream>>>(z, cb, pval, pidx, out,
                                                    out + 2097152, partials);
    finalize_kernel<<<1, 256, 0, stream>>>(partials, NROWS / 16,
                                           out + 2113536);
  } else {
    float* pval = ws + 1073152;
    int* pidx = (int*)(ws + 1105920);
    float* partials = ws + 1138688;

    wprep_kernel<<<DIM, 64, 0, stream>>>(conv_v, conv_g, Wt);
    codebook_kernel<<<NCODE / 16, 256, 0, stream>>>(fc, Wt, conv_b, cb, cnorm2,
                                                    nullptr);
    argmin_kernel<<<256, 256, 0, stream>>>(z, cb, cnorm2, pval, pidx);
    rotate_kernel<<<NROWS / 4, 256, 0, stream>>>(z, cb, pval, pidx, 2, out,
                                                 out + 2097152, partials);
    finalize_kernel<<<1, 256, 0, stream>>>(partials, NROWS / 4,
                                           out + 2113536);
  }
}

// Round 12
// 197.994 us; speedup vs baseline: 1.1193x; 1.1193x over previous
//
#include <hip/hip_runtime.h>
#include <math.h>

#define NROWS 16384  // B*T
#define DIM 128
#define NCODE 8192
#define EPSF 1e-12f

typedef float f32x4 __attribute__((ext_vector_type(4)));
typedef __bf16 bf16x8 __attribute__((ext_vector_type(8)));
typedef unsigned short u16x8 __attribute__((ext_vector_type(8)));

// ---------------- MFMA-path ws layout (float offsets) ----------------
// cb       : 0          (1048576)
// cnorm2   : 1048576    (8192)
// Wt       : 1056768    (16384)   [k][d] f32, scale folded in
// Zcat     : 1073152    (3145728 f32 slots = 16384*384 u16)  [rt128][kt12][128r][32k]
// CBcat    : 4218880    (1572864 f32 slots =  8192*384 u16)  [ct32][kt12][256c][32k]
// pval     : 5791744    (used 524288)  [32 tiles][16384 rows]
// pidx     : 6840320    (used 524288)
// partials : 7888896    (4096)
// end        7892992 floats = 31,571,968 bytes
#define WS_NEED_BYTES 31571968ull

// K = 384 = 12 k-tiles of 32.  Z segs: [hi|hi|lo]; CB segs: [hi|lo|hi].
// Within a chunk [R rows][32 k]: elem(r,k) at (r<<5) + (k ^ (((r>>1)&3)<<3)).
#define KT 12
#define TILEA 4096   // 128*32 elems per (row-tile, kt) chunk
#define TILEB 8192   // 256*32 elems per (code-tile, kt) chunk
#define KPB 3        // k-tiles per barrier-pair (BK=96) -> 72 KiB LDS
#define CHUNK (TILEA + TILEB)  // 12288 elems per staged k-tile

__device__ __forceinline__ float wave_sum(float x) {
#pragma unroll
  for (int off = 32; off > 0; off >>= 1) x += __shfl_xor(x, off, 64);
  return x;
}

__device__ __forceinline__ unsigned short f2bf(float x) {
  union { float f; unsigned int u; } v;
  v.f = x;
  unsigned int r = v.u + 0x7fffu + ((v.u >> 16) & 1u);
  return (unsigned short)(r >> 16);
}
__device__ __forceinline__ float bf2f(unsigned short h) {
  union { float f; unsigned int u; } v;
  v.u = ((unsigned int)h) << 16;
  return v.f;
}

__device__ __forceinline__ void gload_lds16(const unsigned short* g,
                                            unsigned short* l) {
  __builtin_amdgcn_global_load_lds(
      (const __attribute__((address_space(1))) void*)g,
      (__attribute__((address_space(3))) void*)l, 16, 0, 0);
}

// --- K0a (fused): zprep (blocks 0..3071) + wprep (blocks 3072..3103) -----
__global__ __launch_bounds__(256) void wz_kernel(
    const float* __restrict__ z, const float* __restrict__ v,
    const float* __restrict__ g, unsigned short* __restrict__ zcat,
    float* __restrict__ Wt) {
  const int b = blockIdx.x;
  if (b < 3072) {
    const int id = b * 256 + threadIdx.x;  // 16384*48 exact
    const int row = id / 48, s = id - row * 48;
    const int kt = s >> 2, s4 = s & 3;
    const int seg = kt >> 2;  // 0,1: hi   2: lo
    const int d0 = ((kt & 3) << 5) + (s4 << 3);
    const int r = row & 127, rt = row >> 7;
    const int slotsw = s4 ^ ((r >> 1) & 3);

    const float* zp = &z[(size_t)row * DIM + d0];
    u16x8 out;
#pragma unroll
    for (int i = 0; i < 8; ++i) {
      const float x = zp[i];
      unsigned short bb = f2bf(x);
      if (seg == 2) bb = f2bf(x - bf2f(bb));
      out[i] = bb;
    }
    *(u16x8*)&zcat[(size_t)(rt * KT + kt) * TILEA + (r << 5) +
                   (slotsw << 3)] = out;
  } else {
    const int tid = threadIdx.x;
    const int wid = tid >> 6, lane = tid & 63;
    const int d = (b - 3072) * 4 + wid;  // 128 d total
    const float v0 = v[d * DIM + lane], v1 = v[d * DIM + lane + 64];
    const float ss = wave_sum(fmaf(v0, v0, v1 * v1));
    const float sc = g[d] / sqrtf(ss);
    Wt[lane * DIM + d] = v0 * sc;
    Wt[(lane + 64) * DIM + d] = v1 * sc;
  }
}

// --- K0b: cb[c][d] = fc[c]·Wt[:,d] + b[d]; cnorm2; cbcat (256-code tiles)
__global__ __launch_bounds__(256, 2) void codebook_kernel(
    const float* __restrict__ fc, const float* __restrict__ Wt,
    const float* __restrict__ bias, float* __restrict__ cb,
    float* __restrict__ cnorm2, unsigned short* __restrict__ cbcat) {
  __shared__ float Ws[DIM][DIM];  // 64 KiB, [k][d]
  const int tid = threadIdx.x;
  for (int i = tid; i < 4096; i += 256)
    *(float4*)&Ws[0][i << 2] = *(const float4*)&Wt[i << 2];
  __syncthreads();

  const int lane = tid & 63, wid = tid >> 6;
  const int c0 = blockIdx.x * 16 + wid * 4;
  const float b0 = bias[lane], b1 = bias[lane + 64];

  for (int cc = 0; cc < 4; ++cc) {
    const int c = __builtin_amdgcn_readfirstlane(c0 + cc);
    float a0 = 0.f, a1 = 0.f;
    for (int k = 0; k < DIM; k += 4) {
      const float4 f4 = *(const float4*)&fc[c * DIM + k];
      a0 = fmaf(f4.x, Ws[k][lane], a0);
      a1 = fmaf(f4.x, Ws[k][lane + 64], a1);
      a0 = fmaf(f4.y, Ws[k + 1][lane], a0);
      a1 = fmaf(f4.y, Ws[k + 1][lane + 64], a1);
      a0 = fmaf(f4.z, Ws[k + 2][lane], a0);
      a1 = fmaf(f4.z, Ws[k + 2][lane + 64], a1);
      a0 = fmaf(f4.w, Ws[k + 3][lane], a0);
      a1 = fmaf(f4.w, Ws[k + 3][lane + 64], a1);
    }
    const float o0 = a0 + b0, o1 = a1 + b1;
    cb[c * DIM + lane] = o0;
    cb[c * DIM + lane + 64] = o1;
    const float ss = wave_sum(fmaf(o0, o0, o1 * o1));
    if (lane == 0) cnorm2[c] = ss;

    if (cbcat != nullptr) {
      const int ct = c >> 8, r = c & 255;
      const unsigned int swz = ((r >> 1) & 3) << 3;
      unsigned short* base = cbcat + (size_t)ct * (KT * TILEB);
#pragma unroll
      for (int h = 0; h < 2; ++h) {
        const int d = lane + 64 * h;
        const float val = h ? o1 : o0;
        const unsigned short hiv = f2bf(val);
        const unsigned short lov = f2bf(val - bf2f(hiv));
        const int ktl = d >> 5;
        const int off = (r << 5) + ((d & 31) ^ swz);
        base[ktl * TILEB + off] = hiv;        // seg0: hi (pairs Z hi)
        base[(4 + ktl) * TILEB + off] = lov;  // seg1: lo (pairs Z hi)
        base[(8 + ktl) * TILEB + off] = hiv;  // seg2: hi (pairs Z lo)
      }
    }
  }
}

// --- K1: MFMA distance GEMM + per-tile argmin (exact R10 winner) ---------
// 128x256 tile, BK=96 (KPB=3), 4 waves (2x2 grid; wave tile 64x128,
// acc[4][8] -> 0.375 ds_reads/MFMA), single-buffer 72 KiB LDS,
// 2 blocks/CU (2 waves/SIMD; 2 independent barrier groups/CU).
__global__ __launch_bounds__(256, 2) void mfma_argmin_kernel(
    const unsigned short* __restrict__ zcat,
    const unsigned short* __restrict__ cbcat,
    const float* __restrict__ cnorm2, float* __restrict__ pval,
    int* __restrict__ pidx) {
  __shared__ __align__(16) unsigned short S[KPB * CHUNK];  // 72 KiB

  const int xcd = blockIdx.x & 7, idx = blockIdx.x >> 3;  // 4096 % 8 == 0
  const int rt = xcd * 16 + (idx & 15);  // 0..127 row tile (128 rows)
  const int ct = idx >> 4;               // 0..31  code tile (256 codes)

  const int tid = threadIdx.x;
  const int lane = tid & 63, wid = tid >> 6;  // 4 waves
  const int wr = wid >> 1, wc = wid & 1;      // 2 x 2 wave grid
  const int l15 = lane & 15, lg = lane >> 4;
  const int tid8 = tid * 8;  // 256 thr x 8 elems = 2048/issue

  const unsigned short* Ag = zcat + (size_t)rt * (KT * TILEA);
  const unsigned short* Bg = cbcat + (size_t)ct * (KT * TILEB);

  f32x4 acc[4][8];
#pragma unroll
  for (int mi = 0; mi < 4; ++mi)
#pragma unroll
    for (int ni = 0; ni < 8; ++ni) acc[mi][ni] = f32x4{0.f, 0.f, 0.f, 0.f};

  int aoff[4], boff[8];
#pragma unroll
  for (int i = 0; i < 4; ++i) {
    const int ra = wr * 64 + i * 16 + l15;
    aoff[i] = (ra << 5) + ((lg ^ ((ra >> 1) & 3)) << 3);
  }
#pragma unroll
  for (int i = 0; i < 8; ++i) {
    const int rc = wc * 128 + i * 16 + l15;
    boff[i] = TILEA + (rc << 5) + ((lg ^ ((rc >> 1) & 3)) << 3);
  }

  for (int it = 0; it < KT / KPB; ++it) {
    __syncthreads();  // previous iteration's ds_reads complete
#pragma unroll
    for (int kk = 0; kk < KPB; ++kk) {
      const int kt = it * KPB + kk;
      const unsigned short* ag = Ag + kt * TILEA;
      const unsigned short* bg = Bg + kt * TILEB;
      unsigned short* la = &S[kk * CHUNK];
      unsigned short* lb = &S[kk * CHUNK + TILEA];
#pragma unroll
      for (int j = 0; j < 2; ++j)  // A chunk: 4096 elems = 2 issues
        gload_lds16(ag + j * 2048 + tid8, la + j * 2048 + tid8);
#pragma unroll
      for (int j = 0; j < 4; ++j)  // B chunk: 8192 elems = 4 issues
        gload_lds16(bg + j * 2048 + tid8, lb + j * 2048 + tid8);
    }
    __syncthreads();  // vmcnt(0) drain (once per BK=96)

#pragma unroll
    for (int kk = 0; kk < KPB; ++kk) {
      const int sb = kk * CHUNK;
      bf16x8 af[4], bfr[8];
#pragma unroll
      for (int i = 0; i < 4; ++i) af[i] = *(const bf16x8*)&S[sb + aoff[i]];
#pragma unroll
      for (int i = 0; i < 8; ++i) bfr[i] = *(const bf16x8*)&S[sb + boff[i]];
#pragma unroll
      for (int mi = 0; mi < 4; ++mi)
#pragma unroll
        for (int ni = 0; ni < 8; ++ni)
          acc[mi][ni] = __builtin_amdgcn_mfma_f32_16x16x32_bf16(
              af[mi], bfr[ni], acc[mi][ni], 0, 0, 0);
    }
  }
  __syncthreads();  // full drain before LDS overlay

  // ---- epilogue: dist = cn - 2*dot ; argmin over this block's 256 codes
  float* exv = (float*)&S[0];  // [2][128] floats
  int* exi = (int*)&S[2048];   // [2][128] ints (byte offset 4096)

  float cn[8];
#pragma unroll
  for (int ni = 0; ni < 8; ++ni)
    cn[ni] = cnorm2[ct * 256 + wc * 128 + ni * 16 + l15];

#pragma unroll
  for (int mi = 0; mi < 4; ++mi) {
#pragma unroll
    for (int rg = 0; rg < 4; ++rg) {
      float bv = 3.4e38f;
      int bi = 0;
#pragma unroll
      for (int ni = 0; ni < 8; ++ni) {
        const float d = fmaf(-2.f, acc[mi][ni][rg], cn[ni]);
        if (d < bv) { bv = d; bi = ct * 256 + wc * 128 + ni * 16 + l15; }
      }
#pragma unroll
      for (int off = 1; off < 16; off <<= 1) {  // within l15 group
        const float ov = __shfl_xor(bv, off, 64);
        const int oi = __shfl_xor(bi, off, 64);
        if (ov < bv || (ov == bv && oi < bi)) { bv = ov; bi = oi; }
      }
      if (l15 == 0) {
        const int rloc = wr * 64 + mi * 16 + (lg << 2) + rg;
        exv[wc * 128 + rloc] = bv;
        exi[wc * 128 + rloc] = bi;
      }
    }
  }
  __syncthreads();
  if (tid < 128) {
    float bv = exv[tid];
    int bi = exi[tid];
    const float v1 = exv[128 + tid];
    if (v1 < bv) { bv = v1; bi = exi[128 + tid]; }  // tie -> wc=0 (lower code)
    const int row = rt * 128 + tid;
    pval[(size_t)ct * NROWS + row] = bv;
    pidx[(size_t)ct * NROWS + row] = bi;
  }
}

// ===================== fallback path kernels (round-1 style) =============
__global__ void wprep_kernel(const float* __restrict__ v,
                             const float* __restrict__ g,
                             float* __restrict__ Wt) {
  const int d = blockIdx.x;
  const int lane = threadIdx.x;
  const float v0 = v[d * DIM + lane], v1 = v[d * DIM + lane + 64];
  const float ss = wave_sum(fmaf(v0, v0, v1 * v1));
  const float sc = g[d] / sqrtf(ss);
  Wt[lane * DIM + d] = v0 * sc;
  Wt[(lane + 64) * DIM + d] = v1 * sc;
}

__global__ __launch_bounds__(256, 1) void argmin_kernel(
    const float* __restrict__ z, const float* __restrict__ cb,
    const float* __restrict__ cnorm2, float* __restrict__ pval,
    int* __restrict__ pidx) {
  __shared__ float zs[128][DIM];
  __shared__ float cs[128][DIM];

  const int tid = threadIdx.x;
  const int rb = blockIdx.x >> 1;
  const int ch = blockIdx.x & 1;
  const int row0 = rb * 128;
  const int code0 = ch * (NCODE / 2);

  for (int i = tid; i < 128 * 32; i += 256) {
    const int r = i >> 5, f = i & 31;
    *(float4*)&zs[r][f << 2] = *(const float4*)&z[(row0 + r) * DIM + (f << 2)];
  }

  const int tx = tid & 15, ty = tid >> 4;
  const int sw = tx & 7;

  float best[8];
  int besti[8];
#pragma unroll
  for (int r = 0; r < 8; ++r) { best[r] = 3.4e38f; besti[r] = 0; }

  for (int cc = 0; cc < NCODE / 2; cc += 128) {
    __syncthreads();
    for (int i = tid; i < 128 * 32; i += 256) {
      const int r = i >> 5, f = i & 31;
      const int fg = f ^ (r & 7);
      *(float4*)&cs[r][f << 2] =
          *(const float4*)&cb[(code0 + cc + r) * DIM + (fg << 2)];
    }
    __syncthreads();

    float acc[8][8];
#pragma unroll
    for (int r = 0; r < 8; ++r)
#pragma unroll
      for (int j = 0; j < 8; ++j) acc[r][j] = 0.f;

    for (int k = 0; k < DIM; k += 4) {
      const int f = k >> 2;
      float4 zr[8], cr[8];
#pragma unroll
      for (int r = 0; r < 8; ++r) zr[r] = *(const float4*)&zs[ty + 16 * r][k];
      const int col = ((f ^ sw) << 2);
#pragma unroll
      for (int j = 0; j < 8; ++j) cr[j] = *(const float4*)&cs[tx + 16 * j][col];
#pragma unroll
      for (int r = 0; r < 8; ++r)
#pragma unroll
        for (int j = 0; j < 8; ++j) {
          acc[r][j] = fmaf(zr[r].x, cr[j].x, acc[r][j]);
          acc[r][j] = fmaf(zr[r].y, cr[j].y, acc[r][j]);
          acc[r][j] = fmaf(zr[r].z, cr[j].z, acc[r][j]);
          acc[r][j] = fmaf(zr[r].w, cr[j].w, acc[r][j]);
        }
    }

#pragma unroll
    for (int j = 0; j < 8; ++j) {
      const int code = code0 + cc + tx + 16 * j;
      const float cnv = cnorm2[code];
#pragma unroll
      for (int r = 0; r < 8; ++r) {
        const float s = fmaf(-2.f, acc[r][j], cnv);
        if (s < best[r]) { best[r] = s; besti[r] = code; }
      }
    }
  }

#pragma unroll
  for (int off = 1; off < 16; off <<= 1) {
#pragma unroll
    for (int r = 0; r < 8; ++r) {
      const float ov = __shfl_xor(best[r], off, 64);
      const int oi = __shfl_xor(besti[r], off, 64);
      if (ov < best[r] || (ov == best[r] && oi < besti[r])) {
        best[r] = ov;
        besti[r] = oi;
      }
    }
  }
  if (tx == 0) {
#pragma unroll
    for (int r = 0; r < 8; ++r) {
      const int row = row0 + ty + 16 * r;
      pval[(size_t)ch * NROWS + row] = best[r];
      pidx[(size_t)ch * NROWS + row] = besti[r];
    }
  }
}

// --- shared rotation body -------------------------------------------------
__device__ __forceinline__ float rotate_row(const float* __restrict__ z,
                                            const float* __restrict__ cb,
                                            int row, int ci, int lane,
                                            float* __restrict__ out_zq,
                                            float* __restrict__ out_idx) {
  const float z0 = z[row * DIM + lane], z1 = z[row * DIM + lane + 64];
  const float c0 = cb[ci * DIM + lane], c1 = cb[ci * DIM + lane + 64];

  const float ns2 = wave_sum(fmaf(z0, z0, z1 * z1));
  const float nt2 = wave_sum(fmaf(c0, c0, c1 * c1));
  const float ns = sqrtf(ns2), nt = sqrtf(nt2);
  const float dns = fmaxf(ns, EPSF), dnt = fmaxf(nt, EPSF);
  const float u0 = z0 / dns, u1 = z1 / dns;
  const float q0 = c0 / dnt, q1 = c1 / dnt;
  float w0 = u0 + q0, w1 = u1 + q1;
  const float nw = sqrtf(wave_sum(fmaf(w0, w0, w1 * w1)));
  const float dnw = fmaxf(nw, EPSF);
  w0 /= dnw;
  w1 /= dnw;
  const float ew = wave_sum(fmaf(z0, w0, z1 * w1));
  const float eu = wave_sum(fmaf(z0, u0, z1 * u1));
  const float sc = nt / dns;
  const float o0 = (z0 - 2.f * ew * w0 + 2.f * eu * q0) * sc;
  const float o1 = (z1 - 2.f * ew * w1 + 2.f * eu * q1) * sc;
  out_zq[row * DIM + lane] = o0;
  out_zq[row * DIM + lane + 64] = o1;
  if (lane == 0) out_idx[row] = (float)ci;

  const float d0 = z0 - c0, d1 = z1 - c1;
  return wave_sum(fmaf(d0, d0, d1 * d1));
}

// --- K2 (main): 16 rows per block, wave loops 4 rows ----------------------
__global__ __launch_bounds__(256) void rotate16_kernel(
    const float* __restrict__ z, const float* __restrict__ cb,
    const float* __restrict__ pval, const int* __restrict__ pidx,
    float* __restrict__ out_zq, float* __restrict__ out_idx,
    float* __restrict__ partials) {
  const int tid = threadIdx.x;
  const int wid = tid >> 6, lane = tid & 63;
  float acc = 0.f;
#pragma unroll
  for (int j = 0; j < 4; ++j) {
    const int row = blockIdx.x * 16 + wid * 4 + j;
    // lane-parallel reduce over 32 code-tile partials
    float bv = 3.4e38f;
    int bi = 0x7fffffff;
    if (lane < 32) {
      bv = pval[(size_t)lane * NROWS + row];
      bi = pidx[(size_t)lane * NROWS + row];
    }
#pragma unroll
    for (int off = 32; off > 0; off >>= 1) {
      const float ov = __shfl_xor(bv, off, 64);
      const int oi = __shfl_xor(bi, off, 64);
      if (ov < bv || (ov == bv && oi < bi)) { bv = ov; bi = oi; }
    }
    acc += rotate_row(z, cb, row, bi, lane, out_zq, out_idx);
  }
  __shared__ float pr[4];
  if (lane == 0) pr[wid] = acc;
  __syncthreads();
  if (tid == 0) partials[blockIdx.x] = (pr[0] + pr[1]) + (pr[2] + pr[3]);
}

// --- K2 (fallback): 4 rows per block --------------------------------------
__global__ __launch_bounds__(256) void rotate_kernel(
    const float* __restrict__ z, const float* __restrict__ cb,
    const float* __restrict__ pval, const int* __restrict__ pidx, int ntiles,
    float* __restrict__ out_zq, float* __restrict__ out_idx,
    float* __restrict__ partials) {
  const int tid = threadIdx.x;
  const int wid = tid >> 6, lane = tid & 63;
  const int row = blockIdx.x * 4 + wid;

  float bv = 3.4e38f;
  int bi = 0x7fffffff;
  if (lane < ntiles) {
    bv = pval[(size_t)lane * NROWS + row];
    bi = pidx[(size_t)lane * NROWS + row];
  }
#pragma unroll
  for (int off = 32; off > 0; off >>= 1) {
    const float ov = __shfl_xor(bv, off, 64);
    const int oi = __shfl_xor(bi, off, 64);
    if (ov < bv || (ov == bv && oi < bi)) { bv = ov; bi = oi; }
  }
  const float rsum = rotate_row(z, cb, row, bi, lane, out_zq, out_idx);
  __shared__ float pr[4];
  if (lane == 0) pr[wid] = rsum;
  __syncthreads();
  if (tid == 0) partials[blockIdx.x] = (pr[0] + pr[1]) + (pr[2] + pr[3]);
}

// --- K3: deterministic final reduction for commit ------------------------
__global__ void finalize_kernel(const float* __restrict__ partials, int n,
                                float* __restrict__ out_commit) {
  __shared__ float red[256];
  const int tid = threadIdx.x;
  float s = 0.f;
  for (int i = tid; i < n; i += 256) s += partials[i];
  red[tid] = s;
  __syncthreads();
  for (int off = 128; off > 0; off >>= 1) {
    if (tid < off) red[tid] += red[tid + off];
    __syncthreads();
  }
  if (tid == 0) out_commit[0] = red[0] * (1.25f / ((float)NROWS * (float)DIM));
}

extern "C" void kernel_launch(void* const* d_in, const int* in_sizes, int n_in,
                              void* d_out, int out_size, void* d_ws,
                              size_t ws_size, hipStream_t stream) {
  const float* z = (const float*)d_in[0];
  const float* fc = (const float*)d_in[1];
  const float* conv_v = (const float*)d_in[2];
  const float* conv_g = (const float*)d_in[3];
  const float* conv_b = (const float*)d_in[4];
  float* out = (float*)d_out;  // [zq 2097152][idx 16384][commit 1]

  float* ws = (float*)d_ws;
  float* cb = ws;
  float* cnorm2 = ws + 1048576;
  float* Wt = ws + 1056768;

  if (ws_size >= WS_NEED_BYTES) {
    unsigned short* zcat = (unsigned short*)(ws + 1073152);
    unsigned short* cbcat = (unsigned short*)(ws + 4218880);
    float* pval = ws + 5791744;
    int* pidx = (int*)(ws + 6840320);
    float* partials = ws + 7888896;

    wz_kernel<<<3104, 256, 0, stream>>>(z, conv_v, conv_g, zcat, Wt);
    codebook_kernel<<<NCODE / 16, 256, 0, stream>>>(fc, Wt, conv_b, cb, cnorm2,
                                                    cbcat);
    mfma_argmin_kernel<<<4096, 256, 0, stream>>>(zcat, cbcat, cnorm2, pval,
                                                 pidx);
    rotate16_kernel<<<NROWS / 16, 256, 0, stream>>>(z, cb, pval, pidx, out,
                                                    out + 2097152, partials);
    finalize_kernel<<<1, 256, 0, stream>>>(partials, NROWS / 16,
                                           out + 2113536);
  } else {
    float* pval = ws + 1073152;
    int* pidx = (int*)(ws + 1105920);
    float* partials = ws + 1138688;

    wprep_kernel<<<DIM, 64, 0, stream>>>(conv_v, conv_g, Wt);
    codebook_kernel<<<NCODE / 16, 256, 0, stream>>>(fc, Wt, conv_b, cb, cnorm2,
                                                    nullptr);
    argmin_kernel<<<256, 256, 0, stream>>>(z, cb, cnorm2, pval, pidx);
    rotate_kernel<<<NROWS / 4, 256, 0, stream>>>(z, cb, pval, pidx, 2, out,
                                                 out + 2097152, partials);
    finalize_kernel<<<1, 256, 0, stream>>>(partials, NROWS / 4,
                                           out + 2113536);
  }
}

// Round 13
// 196.725 us; speedup vs baseline: 1.1265x; 1.0065x over previous
//
#include <hip/hip_runtime.h>
#include <math.h>

#define NROWS 16384  // B*T
#define DIM 128
#define NCODE 8192
#define EPSF 1e-12f

typedef float f32x4 __attribute__((ext_vector_type(4)));
typedef __bf16 bf16x8 __attribute__((ext_vector_type(8)));
typedef unsigned short u16x8 __attribute__((ext_vector_type(8)));

// ---------------- MFMA-path ws layout (float offsets) ----------------
// cb       : 0          (1048576)
// cnorm2   : 1048576    (8192)
// Wt       : 1056768    (16384)   [k][d] f32, scale folded in
// Zcat     : 1073152    (3145728 f32 slots = 16384*384 u16)  [rt128][kt12][128r][32k]
// CBcat    : 4218880    (1572864 f32 slots =  8192*384 u16)  [ct32][kt12][256c][32k]
// amin     : 5791744    (32768 f32 slots = 16384 u64)  packed (monoval<<32)|idx
// partials : 7888896    (4096)
// end        7892992 floats = 31,571,968 bytes
#define WS_NEED_BYTES 31571968ull

// K = 384 = 12 k-tiles of 32.  Z segs: [hi|hi|lo]; CB segs: [hi|lo|hi].
// Within a chunk [R rows][32 k]: elem(r,k) at (r<<5) + (k ^ (((r>>1)&3)<<3)).
#define KT 12
#define TILEA 4096   // 128*32 elems per (row-tile, kt) chunk
#define TILEB 8192   // 256*32 elems per (code-tile, kt) chunk
#define KPB 3        // k-tiles per barrier-pair (BK=96) -> 72 KiB LDS
#define CHUNK (TILEA + TILEB)  // 12288 elems per staged k-tile

__device__ __forceinline__ float wave_sum(float x) {
#pragma unroll
  for (int off = 32; off > 0; off >>= 1) x += __shfl_xor(x, off, 64);
  return x;
}

__device__ __forceinline__ unsigned short f2bf(float x) {
  union { float f; unsigned int u; } v;
  v.f = x;
  unsigned int r = v.u + 0x7fffu + ((v.u >> 16) & 1u);
  return (unsigned short)(r >> 16);
}
__device__ __forceinline__ float bf2f(unsigned short h) {
  union { float f; unsigned int u; } v;
  v.u = ((unsigned int)h) << 16;
  return v.f;
}

__device__ __forceinline__ void gload_lds16(const unsigned short* g,
                                            unsigned short* l) {
  __builtin_amdgcn_global_load_lds(
      (const __attribute__((address_space(1))) void*)g,
      (__attribute__((address_space(3))) void*)l, 16, 0, 0);
}

// --- K0a (fused): zprep + amin init (blocks 0..3071) + wprep (3072..3103)
__global__ __launch_bounds__(256) void wz_kernel(
    const float* __restrict__ z, const float* __restrict__ v,
    const float* __restrict__ g, unsigned short* __restrict__ zcat,
    float* __restrict__ Wt, unsigned long long* __restrict__ amin) {
  const int b = blockIdx.x;
  if (b < 3072) {
    const int id = b * 256 + threadIdx.x;  // 16384*48 exact
    const int row = id / 48, s = id - row * 48;
    if (s == 0) amin[row] = ~0ull;  // re-init every call (ws not re-poisoned)
    const int kt = s >> 2, s4 = s & 3;
    const int seg = kt >> 2;  // 0,1: hi   2: lo
    const int d0 = ((kt & 3) << 5) + (s4 << 3);
    const int r = row & 127, rt = row >> 7;
    const int slotsw = s4 ^ ((r >> 1) & 3);

    const float* zp = &z[(size_t)row * DIM + d0];
    u16x8 out;
#pragma unroll
    for (int i = 0; i < 8; ++i) {
      const float x = zp[i];
      unsigned short bb = f2bf(x);
      if (seg == 2) bb = f2bf(x - bf2f(bb));
      out[i] = bb;
    }
    *(u16x8*)&zcat[(size_t)(rt * KT + kt) * TILEA + (r << 5) +
                   (slotsw << 3)] = out;
  } else {
    const int tid = threadIdx.x;
    const int wid = tid >> 6, lane = tid & 63;
    const int d = (b - 3072) * 4 + wid;  // 128 d total
    const float v0 = v[d * DIM + lane], v1 = v[d * DIM + lane + 64];
    const float ss = wave_sum(fmaf(v0, v0, v1 * v1));
    const float sc = g[d] / sqrtf(ss);
    Wt[lane * DIM + d] = v0 * sc;
    Wt[(lane + 64) * DIM + d] = v1 * sc;
  }
}

// --- K0b: cb[c][d] = fc[c]·Wt[:,d] + b[d]; cnorm2; cbcat (256-code tiles)
__global__ __launch_bounds__(256, 2) void codebook_kernel(
    const float* __restrict__ fc, const float* __restrict__ Wt,
    const float* __restrict__ bias, float* __restrict__ cb,
    float* __restrict__ cnorm2, unsigned short* __restrict__ cbcat) {
  __shared__ float Ws[DIM][DIM];  // 64 KiB, [k][d]
  const int tid = threadIdx.x;
  for (int i = tid; i < 4096; i += 256)
    *(float4*)&Ws[0][i << 2] = *(const float4*)&Wt[i << 2];
  __syncthreads();

  const int lane = tid & 63, wid = tid >> 6;
  const int c0 = blockIdx.x * 16 + wid * 4;
  const float b0 = bias[lane], b1 = bias[lane + 64];

  for (int cc = 0; cc < 4; ++cc) {
    const int c = __builtin_amdgcn_readfirstlane(c0 + cc);
    float a0 = 0.f, a1 = 0.f;
    for (int k = 0; k < DIM; k += 4) {
      const float4 f4 = *(const float4*)&fc[c * DIM + k];
      a0 = fmaf(f4.x, Ws[k][lane], a0);
      a1 = fmaf(f4.x, Ws[k][lane + 64], a1);
      a0 = fmaf(f4.y, Ws[k + 1][lane], a0);
      a1 = fmaf(f4.y, Ws[k + 1][lane + 64], a1);
      a0 = fmaf(f4.z, Ws[k + 2][lane], a0);
      a1 = fmaf(f4.z, Ws[k + 2][lane + 64], a1);
      a0 = fmaf(f4.w, Ws[k + 3][lane], a0);
      a1 = fmaf(f4.w, Ws[k + 3][lane + 64], a1);
    }
    const float o0 = a0 + b0, o1 = a1 + b1;
    cb[c * DIM + lane] = o0;
    cb[c * DIM + lane + 64] = o1;
    const float ss = wave_sum(fmaf(o0, o0, o1 * o1));
    if (lane == 0) cnorm2[c] = ss;

    if (cbcat != nullptr) {
      const int ct = c >> 8, r = c & 255;
      const unsigned int swz = ((r >> 1) & 3) << 3;
      unsigned short* base = cbcat + (size_t)ct * (KT * TILEB);
#pragma unroll
      for (int h = 0; h < 2; ++h) {
        const int d = lane + 64 * h;
        const float val = h ? o1 : o0;
        const unsigned short hiv = f2bf(val);
        const unsigned short lov = f2bf(val - bf2f(hiv));
        const int ktl = d >> 5;
        const int off = (r << 5) + ((d & 31) ^ swz);
        base[ktl * TILEB + off] = hiv;        // seg0: hi (pairs Z hi)
        base[(4 + ktl) * TILEB + off] = lov;  // seg1: lo (pairs Z hi)
        base[(8 + ktl) * TILEB + off] = hiv;  // seg2: hi (pairs Z lo)
      }
    }
  }
}

// --- K1: MFMA distance GEMM + argmin (R10/R12 champion + atomicMin out) --
// 128x256 tile, BK=96 (KPB=3), 4 waves (2x2 grid; wave tile 64x128,
// acc[4][8] -> 0.375 ds_reads/MFMA), single-buffer 72 KiB LDS,
// 2 blocks/CU (2 waves/SIMD; 2 independent barrier groups/CU).
__global__ __launch_bounds__(256, 2) void mfma_argmin_kernel(
    const unsigned short* __restrict__ zcat,
    const unsigned short* __restrict__ cbcat,
    const float* __restrict__ cnorm2,
    unsigned long long* __restrict__ amin) {
  __shared__ __align__(16) unsigned short S[KPB * CHUNK];  // 72 KiB

  const int xcd = blockIdx.x & 7, idx = blockIdx.x >> 3;  // 4096 % 8 == 0
  const int rt = xcd * 16 + (idx & 15);  // 0..127 row tile (128 rows)
  const int ct = idx >> 4;               // 0..31  code tile (256 codes)

  const int tid = threadIdx.x;
  const int lane = tid & 63, wid = tid >> 6;  // 4 waves
  const int wr = wid >> 1, wc = wid & 1;      // 2 x 2 wave grid
  const int l15 = lane & 15, lg = lane >> 4;
  const int tid8 = tid * 8;  // 256 thr x 8 elems = 2048/issue

  const unsigned short* Ag = zcat + (size_t)rt * (KT * TILEA);
  const unsigned short* Bg = cbcat + (size_t)ct * (KT * TILEB);

  f32x4 acc[4][8];
#pragma unroll
  for (int mi = 0; mi < 4; ++mi)
#pragma unroll
    for (int ni = 0; ni < 8; ++ni) acc[mi][ni] = f32x4{0.f, 0.f, 0.f, 0.f};

  int aoff[4], boff[8];
#pragma unroll
  for (int i = 0; i < 4; ++i) {
    const int ra = wr * 64 + i * 16 + l15;
    aoff[i] = (ra << 5) + ((lg ^ ((ra >> 1) & 3)) << 3);
  }
#pragma unroll
  for (int i = 0; i < 8; ++i) {
    const int rc = wc * 128 + i * 16 + l15;
    boff[i] = TILEA + (rc << 5) + ((lg ^ ((rc >> 1) & 3)) << 3);
  }

  for (int it = 0; it < KT / KPB; ++it) {
    __syncthreads();  // previous iteration's ds_reads complete
#pragma unroll
    for (int kk = 0; kk < KPB; ++kk) {
      const int kt = it * KPB + kk;
      const unsigned short* ag = Ag + kt * TILEA;
      const unsigned short* bg = Bg + kt * TILEB;
      unsigned short* la = &S[kk * CHUNK];
      unsigned short* lb = &S[kk * CHUNK + TILEA];
#pragma unroll
      for (int j = 0; j < 2; ++j)  // A chunk: 4096 elems = 2 issues
        gload_lds16(ag + j * 2048 + tid8, la + j * 2048 + tid8);
#pragma unroll
      for (int j = 0; j < 4; ++j)  // B chunk: 8192 elems = 4 issues
        gload_lds16(bg + j * 2048 + tid8, lb + j * 2048 + tid8);
    }
    __syncthreads();  // vmcnt(0) drain (once per BK=96)

#pragma unroll
    for (int kk = 0; kk < KPB; ++kk) {
      const int sb = kk * CHUNK;
      bf16x8 af[4], bfr[8];
#pragma unroll
      for (int i = 0; i < 4; ++i) af[i] = *(const bf16x8*)&S[sb + aoff[i]];
#pragma unroll
      for (int i = 0; i < 8; ++i) bfr[i] = *(const bf16x8*)&S[sb + boff[i]];
#pragma unroll
      for (int mi = 0; mi < 4; ++mi)
#pragma unroll
        for (int ni = 0; ni < 8; ++ni)
          acc[mi][ni] = __builtin_amdgcn_mfma_f32_16x16x32_bf16(
              af[mi], bfr[ni], acc[mi][ni], 0, 0, 0);
    }
  }
  __syncthreads();  // full drain before LDS overlay

  // ---- epilogue: dist = cn - 2*dot ; argmin over this block's 256 codes
  float* exv = (float*)&S[0];  // [2][128] floats
  int* exi = (int*)&S[2048];   // [2][128] ints (byte offset 4096)

  float cn[8];
#pragma unroll
  for (int ni = 0; ni < 8; ++ni)
    cn[ni] = cnorm2[ct * 256 + wc * 128 + ni * 16 + l15];

#pragma unroll
  for (int mi = 0; mi < 4; ++mi) {
#pragma unroll
    for (int rg = 0; rg < 4; ++rg) {
      float bv = 3.4e38f;
      int bi = 0;
#pragma unroll
      for (int ni = 0; ni < 8; ++ni) {
        const float d = fmaf(-2.f, acc[mi][ni][rg], cn[ni]);
        if (d < bv) { bv = d; bi = ct * 256 + wc * 128 + ni * 16 + l15; }
      }
#pragma unroll
      for (int off = 1; off < 16; off <<= 1) {  // within l15 group
        const float ov = __shfl_xor(bv, off, 64);
        const int oi = __shfl_xor(bi, off, 64);
        if (ov < bv || (ov == bv && oi < bi)) { bv = ov; bi = oi; }
      }
      if (l15 == 0) {
        const int rloc = wr * 64 + mi * 16 + (lg << 2) + rg;
        exv[wc * 128 + rloc] = bv;
        exi[wc * 128 + rloc] = bi;
      }
    }
  }
  __syncthreads();
  if (tid < 128) {
    float bv = exv[tid];
    int bi = exi[tid];
    const float v1 = exv[128 + tid];
    if (v1 < bv) { bv = v1; bi = exi[128 + tid]; }  // tie -> wc=0 (lower code)
    unsigned u = __float_as_uint(bv);
    u ^= (u >> 31) ? 0xFFFFFFFFu : 0x80000000u;  // monotone float->u32
    const unsigned long long packed =
        ((unsigned long long)u << 32) | (unsigned)bi;
    // exact, order-free; ties -> smaller packed = lower code index.
    // 32 atomics per address spread over 16384 addresses: no hotspot.
    atomicMin(&amin[rt * 128 + tid], packed);
  }
}

// ===================== fallback path kernels (round-1 style) =============
__global__ void wprep_kernel(const float* __restrict__ v,
                             const float* __restrict__ g,
                             float* __restrict__ Wt) {
  const int d = blockIdx.x;
  const int lane = threadIdx.x;
  const float v0 = v[d * DIM + lane], v1 = v[d * DIM + lane + 64];
  const float ss = wave_sum(fmaf(v0, v0, v1 * v1));
  const float sc = g[d] / sqrtf(ss);
  Wt[lane * DIM + d] = v0 * sc;
  Wt[(lane + 64) * DIM + d] = v1 * sc;
}

__global__ __launch_bounds__(256, 1) void argmin_kernel(
    const float* __restrict__ z, const float* __restrict__ cb,
    const float* __restrict__ cnorm2, float* __restrict__ pval,
    int* __restrict__ pidx) {
  __shared__ float zs[128][DIM];
  __shared__ float cs[128][DIM];

  const int tid = threadIdx.x;
  const int rb = blockIdx.x >> 1;
  const int ch = blockIdx.x & 1;
  const int row0 = rb * 128;
  const int code0 = ch * (NCODE / 2);

  for (int i = tid; i < 128 * 32; i += 256) {
    const int r = i >> 5, f = i & 31;
    *(float4*)&zs[r][f << 2] = *(const float4*)&z[(row0 + r) * DIM + (f << 2)];
  }

  const int tx = tid & 15, ty = tid >> 4;
  const int sw = tx & 7;

  float best[8];
  int besti[8];
#pragma unroll
  for (int r = 0; r < 8; ++r) { best[r] = 3.4e38f; besti[r] = 0; }

  for (int cc = 0; cc < NCODE / 2; cc += 128) {
    __syncthreads();
    for (int i = tid; i < 128 * 32; i += 256) {
      const int r = i >> 5, f = i & 31;
      const int fg = f ^ (r & 7);
      *(float4*)&cs[r][f << 2] =
          *(const float4*)&cb[(code0 + cc + r) * DIM + (fg << 2)];
    }
    __syncthreads();

    float acc[8][8];
#pragma unroll
    for (int r = 0; r < 8; ++r)
#pragma unroll
      for (int j = 0; j < 8; ++j) acc[r][j] = 0.f;

    for (int k = 0; k < DIM; k += 4) {
      const int f = k >> 2;
      float4 zr[8], cr[8];
#pragma unroll
      for (int r = 0; r < 8; ++r) zr[r] = *(const float4*)&zs[ty + 16 * r][k];
      const int col = ((f ^ sw) << 2);
#pragma unroll
      for (int j = 0; j < 8; ++j) cr[j] = *(const float4*)&cs[tx + 16 * j][col];
#pragma unroll
      for (int r = 0; r < 8; ++r)
#pragma unroll
        for (int j = 0; j < 8; ++j) {
          acc[r][j] = fmaf(zr[r].x, cr[j].x, acc[r][j]);
          acc[r][j] = fmaf(zr[r].y, cr[j].y, acc[r][j]);
          acc[r][j] = fmaf(zr[r].z, cr[j].z, acc[r][j]);
          acc[r][j] = fmaf(zr[r].w, cr[j].w, acc[r][j]);
        }
    }

#pragma unroll
    for (int j = 0; j < 8; ++j) {
      const int code = code0 + cc + tx + 16 * j;
      const float cnv = cnorm2[code];
#pragma unroll
      for (int r = 0; r < 8; ++r) {
        const float s = fmaf(-2.f, acc[r][j], cnv);
        if (s < best[r]) { best[r] = s; besti[r] = code; }
      }
    }
  }

#pragma unroll
  for (int off = 1; off < 16; off <<= 1) {
#pragma unroll
    for (int r = 0; r < 8; ++r) {
      const float ov = __shfl_xor(best[r], off, 64);
      const int oi = __shfl_xor(besti[r], off, 64);
      if (ov < best[r] || (ov == best[r] && oi < besti[r])) {
        best[r] = ov;
        besti[r] = oi;
      }
    }
  }
  if (tx == 0) {
#pragma unroll
    for (int r = 0; r < 8; ++r) {
      const int row = row0 + ty + 16 * r;
      pval[(size_t)ch * NROWS + row] = best[r];
      pidx[(size_t)ch * NROWS + row] = besti[r];
    }
  }
}

// --- shared rotation body -------------------------------------------------
__device__ __forceinline__ float rotate_row(const float* __restrict__ z,
                                            const float* __restrict__ cb,
                                            int row, int ci, int lane,
                                            float* __restrict__ out_zq,
                                            float* __restrict__ out_idx) {
  const float z0 = z[row * DIM + lane], z1 = z[row * DIM + lane + 64];
  const float c0 = cb[ci * DIM + lane], c1 = cb[ci * DIM + lane + 64];

  const float ns2 = wave_sum(fmaf(z0, z0, z1 * z1));
  const float nt2 = wave_sum(fmaf(c0, c0, c1 * c1));
  const float ns = sqrtf(ns2), nt = sqrtf(nt2);
  const float dns = fmaxf(ns, EPSF), dnt = fmaxf(nt, EPSF);
  const float u0 = z0 / dns, u1 = z1 / dns;
  const float q0 = c0 / dnt, q1 = c1 / dnt;
  float w0 = u0 + q0, w1 = u1 + q1;
  const float nw = sqrtf(wave_sum(fmaf(w0, w0, w1 * w1)));
  const float dnw = fmaxf(nw, EPSF);
  w0 /= dnw;
  w1 /= dnw;
  const float ew = wave_sum(fmaf(z0, w0, z1 * w1));
  const float eu = wave_sum(fmaf(z0, u0, z1 * u1));
  const float sc = nt / dns;
  const float o0 = (z0 - 2.f * ew * w0 + 2.f * eu * q0) * sc;
  const float o1 = (z1 - 2.f * ew * w1 + 2.f * eu * q1) * sc;
  out_zq[row * DIM + lane] = o0;
  out_zq[row * DIM + lane + 64] = o1;
  if (lane == 0) out_idx[row] = (float)ci;

  const float d0 = z0 - c0, d1 = z1 - c1;
  return wave_sum(fmaf(d0, d0, d1 * d1));
}

// --- K2 (main): 16 rows per block, amin decode ---------------------------
__global__ __launch_bounds__(256) void rotate16_kernel(
    const float* __restrict__ z, const float* __restrict__ cb,
    const unsigned long long* __restrict__ amin, float* __restrict__ out_zq,
    float* __restrict__ out_idx, float* __restrict__ partials) {
  const int tid = threadIdx.x;
  const int wid = tid >> 6, lane = tid & 63;
  float acc = 0.f;
#pragma unroll
  for (int j = 0; j < 4; ++j) {
    const int row = blockIdx.x * 16 + wid * 4 + j;
    const int ci = (int)(unsigned)(amin[row] & 0xffffffffull);
    acc += rotate_row(z, cb, row, ci, lane, out_zq, out_idx);
  }
  __shared__ float pr[4];
  if (lane == 0) pr[wid] = acc;
  __syncthreads();
  if (tid == 0) partials[blockIdx.x] = (pr[0] + pr[1]) + (pr[2] + pr[3]);
}

// --- K2 (fallback): 4 rows per block, pval/pidx reduce --------------------
__global__ __launch_bounds__(256) void rotate_kernel(
    const float* __restrict__ z, const float* __restrict__ cb,
    const float* __restrict__ pval, const int* __restrict__ pidx, int ntiles,
    float* __restrict__ out_zq, float* __restrict__ out_idx,
    float* __restrict__ partials) {
  const int tid = threadIdx.x;
  const int wid = tid >> 6, lane = tid & 63;
  const int row = blockIdx.x * 4 + wid;

  float bv = 3.4e38f;
  int bi = 0x7fffffff;
  if (lane < ntiles) {
    bv = pval[(size_t)lane * NROWS + row];
    bi = pidx[(size_t)lane * NROWS + row];
  }
#pragma unroll
  for (int off = 32; off > 0; off >>= 1) {
    const float ov = __shfl_xor(bv, off, 64);
    const int oi = __shfl_xor(bi, off, 64);
    if (ov < bv || (ov == bv && oi < bi)) { bv = ov; bi = oi; }
  }
  const float rsum = rotate_row(z, cb, row, bi, lane, out_zq, out_idx);
  __shared__ float pr[4];
  if (lane == 0) pr[wid] = rsum;
  __syncthreads();
  if (tid == 0) partials[blockIdx.x] = (pr[0] + pr[1]) + (pr[2] + pr[3]);
}

// --- K3: deterministic final reduction for commit ------------------------
__global__ void finalize_kernel(const float* __restrict__ partials, int n,
                                float* __restrict__ out_commit) {
  __shared__ float red[256];
  const int tid = threadIdx.x;
  float s = 0.f;
  for (int i = tid; i < n; i += 256) s += partials[i];
  red[tid] = s;
  __syncthreads();
  for (int off = 128; off > 0; off >>= 1) {
    if (tid < off) red[tid] += red[tid + off];
    __syncthreads();
  }
  if (tid == 0) out_commit[0] = red[0] * (1.25f / ((float)NROWS * (float)DIM));
}

extern "C" void kernel_launch(void* const* d_in, const int* in_sizes, int n_in,
                              void* d_out, int out_size, void* d_ws,
                              size_t ws_size, hipStream_t stream) {
  const float* z = (const float*)d_in[0];
  const float* fc = (const float*)d_in[1];
  const float* conv_v = (const float*)d_in[2];
  const float* conv_g = (const float*)d_in[3];
  const float* conv_b = (const float*)d_in[4];
  float* out = (float*)d_out;  // [zq 2097152][idx 16384][commit 1]

  float* ws = (float*)d_ws;
  float* cb = ws;
  float* cnorm2 = ws + 1048576;
  float* Wt = ws + 1056768;

  if (ws_size >= WS_NEED_BYTES) {
    unsigned short* zcat = (unsigned short*)(ws + 1073152);
    unsigned short* cbcat = (unsigned short*)(ws + 4218880);
    unsigned long long* amin = (unsigned long long*)(ws + 5791744);
    float* partials = ws + 7888896;

    wz_kernel<<<3104, 256, 0, stream>>>(z, conv_v, conv_g, zcat, Wt, amin);
    codebook_kernel<<<NCODE / 16, 256, 0, stream>>>(fc, Wt, conv_b, cb, cnorm2,
                                                    cbcat);
    mfma_argmin_kernel<<<4096, 256, 0, stream>>>(zcat, cbcat, cnorm2, amin);
    rotate16_kernel<<<NROWS / 16, 256, 0, stream>>>(z, cb, amin, out,
                                                    out + 2097152, partials);
    finalize_kernel<<<1, 256, 0, stream>>>(partials, NROWS / 16,
                                           out + 2113536);
  } else {
    float* pval = ws + 1073152;
    int* pidx = (int*)(ws + 1105920);
    float* partials = ws + 1138688;

    wprep_kernel<<<DIM, 64, 0, stream>>>(conv_v, conv_g, Wt);
    codebook_kernel<<<NCODE / 16, 256, 0, stream>>>(fc, Wt, conv_b, cb, cnorm2,
                                                    nullptr);
    argmin_kernel<<<256, 256, 0, stream>>>(z, cb, cnorm2, pval, pidx);
    rotate_kernel<<<NROWS / 4, 256, 0, stream>>>(z, cb, pval, pidx, 2, out,
                                                 out + 2097152, partials);
    finalize_kernel<<<1, 256, 0, stream>>>(partials, NROWS / 4,
                                           out + 2113536);
  }
}

// Round 14
// 196.684 us; speedup vs baseline: 1.1267x; 1.0002x over previous
//
#include <hip/hip_runtime.h>
#include <math.h>

#define NROWS 16384  // B*T
#define DIM 128
#define NCODE 8192
#define EPSF 1e-12f

typedef float f32x4 __attribute__((ext_vector_type(4)));
typedef __bf16 bf16x8 __attribute__((ext_vector_type(8)));
typedef unsigned short u16x8 __attribute__((ext_vector_type(8)));

// ---------------- MFMA-path ws layout (float offsets) ----------------
// cb       : 0          (1048576)
// cnorm2   : 1048576    (8192)
// Wt       : 1056768    (16384)   [k][d] f32, scale folded in
// Zcat     : 1073152    (3145728 f32 slots = 16384*384 u16)  [rt128][kt12][128r][32k]
// CBcat    : 4218880    (1572864 f32 slots =  8192*384 u16)  [ct32][kt12][256c][32k]
// amin     : 5791744    (32768 f32 slots = 16384 u64)  packed (monoval<<32)|idx
// partials : 7888896    (4096)
// end        7892992 floats = 31,571,968 bytes
#define WS_NEED_BYTES 31571968ull

// K = 384 = 12 k-tiles of 32.  Z segs: [hi|hi|lo]; CB segs: [hi|lo|hi].
// Within a chunk [R rows][32 k]: elem(r,k) at (r<<5) + (k ^ (((r>>1)&3)<<3)).
#define KT 12
#define TILEA 4096   // 128*32 elems per (row-tile, kt) chunk
#define TILEB 8192   // 256*32 elems per (code-tile, kt) chunk
#define KPB 3        // k-tiles per barrier-pair (BK=96) -> 72 KiB LDS
#define CHUNK (TILEA + TILEB)  // 12288 elems per staged k-tile

__device__ __forceinline__ float wave_sum(float x) {
#pragma unroll
  for (int off = 32; off > 0; off >>= 1) x += __shfl_xor(x, off, 64);
  return x;
}

__device__ __forceinline__ unsigned short f2bf(float x) {
  union { float f; unsigned int u; } v;
  v.f = x;
  unsigned int r = v.u + 0x7fffu + ((v.u >> 16) & 1u);
  return (unsigned short)(r >> 16);
}
__device__ __forceinline__ float bf2f(unsigned short h) {
  union { float f; unsigned int u; } v;
  v.u = ((unsigned int)h) << 16;
  return v.f;
}

__device__ __forceinline__ void gload_lds16(const unsigned short* g,
                                            unsigned short* l) {
  __builtin_amdgcn_global_load_lds(
      (const __attribute__((address_space(1))) void*)g,
      (__attribute__((address_space(3))) void*)l, 16, 0, 0);
}

// --- K0a: Wt[k][d] = v[d][k]*g[d]/||v[d]|| + amin re-init ----------------
// 32 blocks x 256 thr: 4 d per block; each thread inits 2 amin entries.
__global__ __launch_bounds__(256) void wa_kernel(
    const float* __restrict__ v, const float* __restrict__ g,
    float* __restrict__ Wt, unsigned long long* __restrict__ amin) {
  const int tid = threadIdx.x;
  const int gid = blockIdx.x * 256 + tid;  // [0, 8192)
  amin[gid * 2] = ~0ull;  // re-init every call (ws not re-poisoned)
  amin[gid * 2 + 1] = ~0ull;
  const int wid = tid >> 6, lane = tid & 63;
  const int d = blockIdx.x * 4 + wid;  // 128 d total
  const float v0 = v[d * DIM + lane], v1 = v[d * DIM + lane + 64];
  const float ss = wave_sum(fmaf(v0, v0, v1 * v1));
  const float sc = g[d] / sqrtf(ss);
  Wt[lane * DIM + d] = v0 * sc;
  Wt[(lane + 64) * DIM + d] = v1 * sc;
}

// --- K0b (fused): codebook (blocks 0..511) + zprep (blocks 512..3583) ----
// Independent given Wt; one launch packs both across the CUs.
__global__ __launch_bounds__(256, 2) void cbz_kernel(
    const float* __restrict__ fc, const float* __restrict__ Wt,
    const float* __restrict__ bias, const float* __restrict__ z,
    float* __restrict__ cb, float* __restrict__ cnorm2,
    unsigned short* __restrict__ cbcat, unsigned short* __restrict__ zcat) {
  __shared__ float Ws[DIM][DIM];  // 64 KiB, [k][d] (codebook blocks only)
  const int b = blockIdx.x;
  const int tid = threadIdx.x;

  if (b >= 512) {  // ---------------- zprep ----------------
    const int id = (b - 512) * 256 + tid;  // 16384*48 exact
    const int row = id / 48, s = id - row * 48;
    const int kt = s >> 2, s4 = s & 3;
    const int seg = kt >> 2;  // 0,1: hi   2: lo
    const int d0 = ((kt & 3) << 5) + (s4 << 3);
    const int r = row & 127, rt = row >> 7;
    const int slotsw = s4 ^ ((r >> 1) & 3);

    const float* zp = &z[(size_t)row * DIM + d0];
    u16x8 out;
#pragma unroll
    for (int i = 0; i < 8; ++i) {
      const float x = zp[i];
      unsigned short bb = f2bf(x);
      if (seg == 2) bb = f2bf(x - bf2f(bb));
      out[i] = bb;
    }
    *(u16x8*)&zcat[(size_t)(rt * KT + kt) * TILEA + (r << 5) +
                   (slotsw << 3)] = out;
    return;
  }

  // ---------------- codebook ----------------
  for (int i = tid; i < 4096; i += 256)
    *(float4*)&Ws[0][i << 2] = *(const float4*)&Wt[i << 2];
  __syncthreads();

  const int lane = tid & 63, wid = tid >> 6;
  const int c0 = b * 16 + wid * 4;
  const float b0 = bias[lane], b1 = bias[lane + 64];

  for (int cc = 0; cc < 4; ++cc) {
    const int c = __builtin_amdgcn_readfirstlane(c0 + cc);
    float a0 = 0.f, a1 = 0.f;
    for (int k = 0; k < DIM; k += 4) {
      const float4 f4 = *(const float4*)&fc[c * DIM + k];
      a0 = fmaf(f4.x, Ws[k][lane], a0);
      a1 = fmaf(f4.x, Ws[k][lane + 64], a1);
      a0 = fmaf(f4.y, Ws[k + 1][lane], a0);
      a1 = fmaf(f4.y, Ws[k + 1][lane + 64], a1);
      a0 = fmaf(f4.z, Ws[k + 2][lane], a0);
      a1 = fmaf(f4.z, Ws[k + 2][lane + 64], a1);
      a0 = fmaf(f4.w, Ws[k + 3][lane], a0);
      a1 = fmaf(f4.w, Ws[k + 3][lane + 64], a1);
    }
    const float o0 = a0 + b0, o1 = a1 + b1;
    cb[c * DIM + lane] = o0;
    cb[c * DIM + lane + 64] = o1;
    const float ss = wave_sum(fmaf(o0, o0, o1 * o1));
    if (lane == 0) cnorm2[c] = ss;

    const int ct = c >> 8, r = c & 255;
    const unsigned int swz = ((r >> 1) & 3) << 3;
    unsigned short* base = cbcat + (size_t)ct * (KT * TILEB);
#pragma unroll
    for (int h = 0; h < 2; ++h) {
      const int d = lane + 64 * h;
      const float val = h ? o1 : o0;
      const unsigned short hiv = f2bf(val);
      const unsigned short lov = f2bf(val - bf2f(hiv));
      const int ktl = d >> 5;
      const int off = (r << 5) + ((d & 31) ^ swz);
      base[ktl * TILEB + off] = hiv;        // seg0: hi (pairs Z hi)
      base[(4 + ktl) * TILEB + off] = lov;  // seg1: lo (pairs Z hi)
      base[(8 + ktl) * TILEB + off] = hiv;  // seg2: hi (pairs Z lo)
    }
  }
}

// --- K1: MFMA distance GEMM + argmin (R10/R12 champion + T5 setprio) -----
// 128x256 tile, BK=96 (KPB=3), 4 waves (2x2 grid; wave tile 64x128,
// acc[4][8] -> 0.375 ds_reads/MFMA), single-buffer 72 KiB LDS,
// 2 blocks/CU (2 independent barrier groups/CU -> wave role diversity;
// setprio(1) lets MFMA-phase waves preempt the other block's staging).
__global__ __launch_bounds__(256, 2) void mfma_argmin_kernel(
    const unsigned short* __restrict__ zcat,
    const unsigned short* __restrict__ cbcat,
    const float* __restrict__ cnorm2,
    unsigned long long* __restrict__ amin) {
  __shared__ __align__(16) unsigned short S[KPB * CHUNK];  // 72 KiB

  const int xcd = blockIdx.x & 7, idx = blockIdx.x >> 3;  // 4096 % 8 == 0
  const int rt = xcd * 16 + (idx & 15);  // 0..127 row tile (128 rows)
  const int ct = idx >> 4;               // 0..31  code tile (256 codes)

  const int tid = threadIdx.x;
  const int lane = tid & 63, wid = tid >> 6;  // 4 waves
  const int wr = wid >> 1, wc = wid & 1;      // 2 x 2 wave grid
  const int l15 = lane & 15, lg = lane >> 4;
  const int tid8 = tid * 8;  // 256 thr x 8 elems = 2048/issue

  const unsigned short* Ag = zcat + (size_t)rt * (KT * TILEA);
  const unsigned short* Bg = cbcat + (size_t)ct * (KT * TILEB);

  f32x4 acc[4][8];
#pragma unroll
  for (int mi = 0; mi < 4; ++mi)
#pragma unroll
    for (int ni = 0; ni < 8; ++ni) acc[mi][ni] = f32x4{0.f, 0.f, 0.f, 0.f};

  int aoff[4], boff[8];
#pragma unroll
  for (int i = 0; i < 4; ++i) {
    const int ra = wr * 64 + i * 16 + l15;
    aoff[i] = (ra << 5) + ((lg ^ ((ra >> 1) & 3)) << 3);
  }
#pragma unroll
  for (int i = 0; i < 8; ++i) {
    const int rc = wc * 128 + i * 16 + l15;
    boff[i] = TILEA + (rc << 5) + ((lg ^ ((rc >> 1) & 3)) << 3);
  }

  for (int it = 0; it < KT / KPB; ++it) {
    __syncthreads();  // previous iteration's ds_reads complete
#pragma unroll
    for (int kk = 0; kk < KPB; ++kk) {
      const int kt = it * KPB + kk;
      const unsigned short* ag = Ag + kt * TILEA;
      const unsigned short* bg = Bg + kt * TILEB;
      unsigned short* la = &S[kk * CHUNK];
      unsigned short* lb = &S[kk * CHUNK + TILEA];
#pragma unroll
      for (int j = 0; j < 2; ++j)  // A chunk: 4096 elems = 2 issues
        gload_lds16(ag + j * 2048 + tid8, la + j * 2048 + tid8);
#pragma unroll
      for (int j = 0; j < 4; ++j)  // B chunk: 8192 elems = 4 issues
        gload_lds16(bg + j * 2048 + tid8, lb + j * 2048 + tid8);
    }
    __syncthreads();  // vmcnt(0) drain (once per BK=96)

#pragma unroll
    for (int kk = 0; kk < KPB; ++kk) {
      const int sb = kk * CHUNK;
      bf16x8 af[4], bfr[8];
#pragma unroll
      for (int i = 0; i < 4; ++i) af[i] = *(const bf16x8*)&S[sb + aoff[i]];
#pragma unroll
      for (int i = 0; i < 8; ++i) bfr[i] = *(const bf16x8*)&S[sb + boff[i]];
      __builtin_amdgcn_s_setprio(1);
#pragma unroll
      for (int mi = 0; mi < 4; ++mi)
#pragma unroll
        for (int ni = 0; ni < 8; ++ni)
          acc[mi][ni] = __builtin_amdgcn_mfma_f32_16x16x32_bf16(
              af[mi], bfr[ni], acc[mi][ni], 0, 0, 0);
      __builtin_amdgcn_s_setprio(0);
    }
  }
  __syncthreads();  // full drain before LDS overlay

  // ---- epilogue: dist = cn - 2*dot ; argmin over this block's 256 codes
  float* exv = (float*)&S[0];  // [2][128] floats
  int* exi = (int*)&S[2048];   // [2][128] ints (byte offset 4096)

  float cn[8];
#pragma unroll
  for (int ni = 0; ni < 8; ++ni)
    cn[ni] = cnorm2[ct * 256 + wc * 128 + ni * 16 + l15];

#pragma unroll
  for (int mi = 0; mi < 4; ++mi) {
#pragma unroll
    for (int rg = 0; rg < 4; ++rg) {
      float bv = 3.4e38f;
      int bi = 0;
#pragma unroll
      for (int ni = 0; ni < 8; ++ni) {
        const float d = fmaf(-2.f, acc[mi][ni][rg], cn[ni]);
        if (d < bv) { bv = d; bi = ct * 256 + wc * 128 + ni * 16 + l15; }
      }
#pragma unroll
      for (int off = 1; off < 16; off <<= 1) {  // within l15 group
        const float ov = __shfl_xor(bv, off, 64);
        const int oi = __shfl_xor(bi, off, 64);
        if (ov < bv || (ov == bv && oi < bi)) { bv = ov; bi = oi; }
      }
      if (l15 == 0) {
        const int rloc = wr * 64 + mi * 16 + (lg << 2) + rg;
        exv[wc * 128 + rloc] = bv;
        exi[wc * 128 + rloc] = bi;
      }
    }
  }
  __syncthreads();
  if (tid < 128) {
    float bv = exv[tid];
    int bi = exi[tid];
    const float v1 = exv[128 + tid];
    if (v1 < bv) { bv = v1; bi = exi[128 + tid]; }  // tie -> wc=0 (lower code)
    unsigned u = __float_as_uint(bv);
    u ^= (u >> 31) ? 0xFFFFFFFFu : 0x80000000u;  // monotone float->u32
    const unsigned long long packed =
        ((unsigned long long)u << 32) | (unsigned)bi;
    // exact, order-free; ties -> smaller packed = lower code index.
    atomicMin(&amin[rt * 128 + tid], packed);
  }
}

// ===================== fallback path kernels (round-1 style) =============
__global__ void wprep_kernel(const float* __restrict__ v,
                             const float* __restrict__ g,
                             float* __restrict__ Wt) {
  const int d = blockIdx.x;
  const int lane = threadIdx.x;
  const float v0 = v[d * DIM + lane], v1 = v[d * DIM + lane + 64];
  const float ss = wave_sum(fmaf(v0, v0, v1 * v1));
  const float sc = g[d] / sqrtf(ss);
  Wt[lane * DIM + d] = v0 * sc;
  Wt[(lane + 64) * DIM + d] = v1 * sc;
}

__global__ __launch_bounds__(256, 2) void codebook_kernel(
    const float* __restrict__ fc, const float* __restrict__ Wt,
    const float* __restrict__ bias, float* __restrict__ cb,
    float* __restrict__ cnorm2) {
  __shared__ float Ws[DIM][DIM];
  const int tid = threadIdx.x;
  for (int i = tid; i < 4096; i += 256)
    *(float4*)&Ws[0][i << 2] = *(const float4*)&Wt[i << 2];
  __syncthreads();

  const int lane = tid & 63, wid = tid >> 6;
  const int c0 = blockIdx.x * 16 + wid * 4;
  const float b0 = bias[lane], b1 = bias[lane + 64];

  for (int cc = 0; cc < 4; ++cc) {
    const int c = __builtin_amdgcn_readfirstlane(c0 + cc);
    float a0 = 0.f, a1 = 0.f;
    for (int k = 0; k < DIM; k += 4) {
      const float4 f4 = *(const float4*)&fc[c * DIM + k];
      a0 = fmaf(f4.x, Ws[k][lane], a0);
      a1 = fmaf(f4.x, Ws[k][lane + 64], a1);
      a0 = fmaf(f4.y, Ws[k + 1][lane], a0);
      a1 = fmaf(f4.y, Ws[k + 1][lane + 64], a1);
      a0 = fmaf(f4.z, Ws[k + 2][lane], a0);
      a1 = fmaf(f4.z, Ws[k + 2][lane + 64], a1);
      a0 = fmaf(f4.w, Ws[k + 3][lane], a0);
      a1 = fmaf(f4.w, Ws[k + 3][lane + 64], a1);
    }
    const float o0 = a0 + b0, o1 = a1 + b1;
    cb[c * DIM + lane] = o0;
    cb[c * DIM + lane + 64] = o1;
    const float ss = wave_sum(fmaf(o0, o0, o1 * o1));
    if (lane == 0) cnorm2[c] = ss;
  }
}

__global__ __launch_bounds__(256, 1) void argmin_kernel(
    const float* __restrict__ z, const float* __restrict__ cb,
    const float* __restrict__ cnorm2, float* __restrict__ pval,
    int* __restrict__ pidx) {
  __shared__ float zs[128][DIM];
  __shared__ float cs[128][DIM];

  const int tid = threadIdx.x;
  const int rb = blockIdx.x >> 1;
  const int ch = blockIdx.x & 1;
  const int row0 = rb * 128;
  const int code0 = ch * (NCODE / 2);

  for (int i = tid; i < 128 * 32; i += 256) {
    const int r = i >> 5, f = i & 31;
    *(float4*)&zs[r][f << 2] = *(const float4*)&z[(row0 + r) * DIM + (f << 2)];
  }

  const int tx = tid & 15, ty = tid >> 4;
  const int sw = tx & 7;

  float best[8];
  int besti[8];
#pragma unroll
  for (int r = 0; r < 8; ++r) { best[r] = 3.4e38f; besti[r] = 0; }

  for (int cc = 0; cc < NCODE / 2; cc += 128) {
    __syncthreads();
    for (int i = tid; i < 128 * 32; i += 256) {
      const int r = i >> 5, f = i & 31;
      const int fg = f ^ (r & 7);
      *(float4*)&cs[r][f << 2] =
          *(const float4*)&cb[(code0 + cc + r) * DIM + (fg << 2)];
    }
    __syncthreads();

    float acc[8][8];
#pragma unroll
    for (int r = 0; r < 8; ++r)
#pragma unroll
      for (int j = 0; j < 8; ++j) acc[r][j] = 0.f;

    for (int k = 0; k < DIM; k += 4) {
      const int f = k >> 2;
      float4 zr[8], cr[8];
#pragma unroll
      for (int r = 0; r < 8; ++r) zr[r] = *(const float4*)&zs[ty + 16 * r][k];
      const int col = ((f ^ sw) << 2);
#pragma unroll
      for (int j = 0; j < 8; ++j) cr[j] = *(const float4*)&cs[tx + 16 * j][col];
#pragma unroll
      for (int r = 0; r < 8; ++r)
#pragma unroll
        for (int j = 0; j < 8; ++j) {
          acc[r][j] = fmaf(zr[r].x, cr[j].x, acc[r][j]);
          acc[r][j] = fmaf(zr[r].y, cr[j].y, acc[r][j]);
          acc[r][j] = fmaf(zr[r].z, cr[j].z, acc[r][j]);
          acc[r][j] = fmaf(zr[r].w, cr[j].w, acc[r][j]);
        }
    }

#pragma unroll
    for (int j = 0; j < 8; ++j) {
      const int code = code0 + cc + tx + 16 * j;
      const float cnv = cnorm2[code];
#pragma unroll
      for (int r = 0; r < 8; ++r) {
        const float s = fmaf(-2.f, acc[r][j], cnv);
        if (s < best[r]) { best[r] = s; besti[r] = code; }
      }
    }
  }

#pragma unroll
  for (int off = 1; off < 16; off <<= 1) {
#pragma unroll
    for (int r = 0; r < 8; ++r) {
      const float ov = __shfl_xor(best[r], off, 64);
      const int oi = __shfl_xor(besti[r], off, 64);
      if (ov < best[r] || (ov == best[r] && oi < besti[r])) {
        best[r] = ov;
        besti[r] = oi;
      }
    }
  }
  if (tx == 0) {
#pragma unroll
    for (int r = 0; r < 8; ++r) {
      const int row = row0 + ty + 16 * r;
      pval[(size_t)ch * NROWS + row] = best[r];
      pidx[(size_t)ch * NROWS + row] = besti[r];
    }
  }
}

// --- shared rotation body -------------------------------------------------
__device__ __forceinline__ float rotate_row(const float* __restrict__ z,
                                            const float* __restrict__ cb,
                                            int row, int ci, int lane,
                                            float* __restrict__ out_zq,
                                            float* __restrict__ out_idx) {
  const float z0 = z[row * DIM + lane], z1 = z[row * DIM + lane + 64];
  const float c0 = cb[ci * DIM + lane], c1 = cb[ci * DIM + lane + 64];

  const float ns2 = wave_sum(fmaf(z0, z0, z1 * z1));
  const float nt2 = wave_sum(fmaf(c0, c0, c1 * c1));
  const float ns = sqrtf(ns2), nt = sqrtf(nt2);
  const float dns = fmaxf(ns, EPSF), dnt = fmaxf(nt, EPSF);
  const float u0 = z0 / dns, u1 = z1 / dns;
  const float q0 = c0 / dnt, q1 = c1 / dnt;
  float w0 = u0 + q0, w1 = u1 + q1;
  const float nw = sqrtf(wave_sum(fmaf(w0, w0, w1 * w1)));
  const float dnw = fmaxf(nw, EPSF);
  w0 /= dnw;
  w1 /= dnw;
  const float ew = wave_sum(fmaf(z0, w0, z1 * w1));
  const float eu = wave_sum(fmaf(z0, u0, z1 * u1));
  const float sc = nt / dns;
  const float o0 = (z0 - 2.f * ew * w0 + 2.f * eu * q0) * sc;
  const float o1 = (z1 - 2.f * ew * w1 + 2.f * eu * q1) * sc;
  out_zq[row * DIM + lane] = o0;
  out_zq[row * DIM + lane + 64] = o1;
  if (lane == 0) out_idx[row] = (float)ci;

  const float d0 = z0 - c0, d1 = z1 - c1;
  return wave_sum(fmaf(d0, d0, d1 * d1));
}

// --- K2 (main): 16 rows per block, amin decode ---------------------------
__global__ __launch_bounds__(256) void rotate16_kernel(
    const float* __restrict__ z, const float* __restrict__ cb,
    const unsigned long long* __restrict__ amin, float* __restrict__ out_zq,
    float* __restrict__ out_idx, float* __restrict__ partials) {
  const int tid = threadIdx.x;
  const int wid = tid >> 6, lane = tid & 63;
  float acc = 0.f;
#pragma unroll
  for (int j = 0; j < 4; ++j) {
    const int row = blockIdx.x * 16 + wid * 4 + j;
    const int ci = (int)(unsigned)(amin[row] & 0xffffffffull);
    acc += rotate_row(z, cb, row, ci, lane, out_zq, out_idx);
  }
  __shared__ float pr[4];
  if (lane == 0) pr[wid] = acc;
  __syncthreads();
  if (tid == 0) partials[blockIdx.x] = (pr[0] + pr[1]) + (pr[2] + pr[3]);
}

// --- K2 (fallback): 4 rows per block, pval/pidx reduce --------------------
__global__ __launch_bounds__(256) void rotate_kernel(
    const float* __restrict__ z, const float* __restrict__ cb,
    const float* __restrict__ pval, const int* __restrict__ pidx, int ntiles,
    float* __restrict__ out_zq, float* __restrict__ out_idx,
    float* __restrict__ partials) {
  const int tid = threadIdx.x;
  const int wid = tid >> 6, lane = tid & 63;
  const int row = blockIdx.x * 4 + wid;

  float bv = 3.4e38f;
  int bi = 0x7fffffff;
  if (lane < ntiles) {
    bv = pval[(size_t)lane * NROWS + row];
    bi = pidx[(size_t)lane * NROWS + row];
  }
#pragma unroll
  for (int off = 32; off > 0; off >>= 1) {
    const float ov = __shfl_xor(bv, off, 64);
    const int oi = __shfl_xor(bi, off, 64);
    if (ov < bv || (ov == bv && oi < bi)) { bv = ov; bi = oi; }
  }
  const float rsum = rotate_row(z, cb, row, bi, lane, out_zq, out_idx);
  __shared__ float pr[4];
  if (lane == 0) pr[wid] = rsum;
  __syncthreads();
  if (tid == 0) partials[blockIdx.x] = (pr[0] + pr[1]) + (pr[2] + pr[3]);
}

// --- K3: deterministic final reduction for commit ------------------------
__global__ void finalize_kernel(const float* __restrict__ partials, int n,
                                float* __restrict__ out_commit) {
  __shared__ float red[256];
  const int tid = threadIdx.x;
  float s = 0.f;
  for (int i = tid; i < n; i += 256) s += partials[i];
  red[tid] = s;
  __syncthreads();
  for (int off = 128; off > 0; off >>= 1) {
    if (tid < off) red[tid] += red[tid + off];
    __syncthreads();
  }
  if (tid == 0) out_commit[0] = red[0] * (1.25f / ((float)NROWS * (float)DIM));
}

extern "C" void kernel_launch(void* const* d_in, const int* in_sizes, int n_in,
                              void* d_out, int out_size, void* d_ws,
                              size_t ws_size, hipStream_t stream) {
  const float* z = (const float*)d_in[0];
  const float* fc = (const float*)d_in[1];
  const float* conv_v = (const float*)d_in[2];
  const float* conv_g = (const float*)d_in[3];
  const float* conv_b = (const float*)d_in[4];
  float* out = (float*)d_out;  // [zq 2097152][idx 16384][commit 1]

  float* ws = (float*)d_ws;
  float* cb = ws;
  float* cnorm2 = ws + 1048576;
  float* Wt = ws + 1056768;

  if (ws_size >= WS_NEED_BYTES) {
    unsigned short* zcat = (unsigned short*)(ws + 1073152);
    unsigned short* cbcat = (unsigned short*)(ws + 4218880);
    unsigned long long* amin = (unsigned long long*)(ws + 5791744);
    float* partials = ws + 7888896;

    wa_kernel<<<32, 256, 0, stream>>>(conv_v, conv_g, Wt, amin);
    cbz_kernel<<<3584, 256, 0, stream>>>(fc, Wt, conv_b, z, cb, cnorm2, cbcat,
                                         zcat);
    mfma_argmin_kernel<<<4096, 256, 0, stream>>>(zcat, cbcat, cnorm2, amin);
    rotate16_kernel<<<NROWS / 16, 256, 0, stream>>>(z, cb, amin, out,
                                                    out + 2097152, partials);
    finalize_kernel<<<1, 256, 0, stream>>>(partials, NROWS / 16,
                                           out + 2113536);
  } else {
    float* pval = ws + 1073152;
    int* pidx = (int*)(ws + 1105920);
    float* partials = ws + 1138688;

    wprep_kernel<<<DIM, 64, 0, stream>>>(conv_v, conv_g, Wt);
    codebook_kernel<<<NCODE / 16, 256, 0, stream>>>(fc, Wt, conv_b, cb,
                                                    cnorm2);
    argmin_kernel<<<256, 256, 0, stream>>>(z, cb, cnorm2, pval, pidx);
    rotate_kernel<<<NROWS / 4, 256, 0, stream>>>(z, cb, pval, pidx, 2, out,
                                                 out + 2097152, partials);
    finalize_kernel<<<1, 256, 0, stream>>>(partials, NROWS / 4,
                                           out + 2113536);
  }
}